// Round 3
// baseline (7446.406 us; speedup 1.0000x reference)
//
#include <hip/hip_runtime.h>
#include <hip/hip_bf16.h>
#include <math.h>

#define D_MODEL 1024
#define NHEADS  16
#define HDIM    64
#define NEXP    8
#define FFH     2048
#define BATCH   2
#define SEQ     1024
#define NTOK    2048
#define VOCAB   32000

typedef __attribute__((ext_vector_type(4))) float f32x4;
typedef __attribute__((ext_vector_type(8))) __bf16 bf16x8;
typedef __attribute__((ext_vector_type(4))) unsigned short u16x4;

__device__ __forceinline__ unsigned short f2bf(float f) {
    union { float f; unsigned u; } v; v.f = f;
    unsigned r = v.u + 0x7FFFu + ((v.u >> 16) & 1u);
    return (unsigned short)(r >> 16);
}
__device__ __forceinline__ float bf2f(unsigned short u) {
    union { unsigned u; float f; } v; v.u = ((unsigned)u) << 16; return v.f;
}
// split x into hi+mid+lo bf16 (captures ~26 mantissa bits)
__device__ __forceinline__ void split3(float x, unsigned short& h, unsigned short& m, unsigned short& l) {
    h = f2bf(x);
    float r1 = x - bf2f(h);
    m = f2bf(r1);
    float r2 = r1 - bf2f(m);
    l = f2bf(r2);
}

#define MFMA(a, b, c) __builtin_amdgcn_mfma_f32_16x16x32_bf16((a), (b), (c), 0, 0, 0)

// ---------------- split-bf16 MFMA GEMM (f32-accurate) ----------------
// C[M,N] = A[M,K] @ B[K,N], f32 in/out.
// SPLIT: 1 = plain bf16 (1 product), 3 = hi/mid/lo (6 products)
// BT: B stored N-major (NxK). EPI: 0 none, 1 C=acc+addsrc.
// GROUPED: blockIdx.z = expert. GATHER: A row via rowidx. SWAP: swap bx/by.
template<int SPLIT, int BT, int EPI, int GROUPED, int GATHER, int SWAP>
__global__ __launch_bounds__(256) void gemm_kernel(
    const float* __restrict__ A, const float* __restrict__ Bmat,
    float* C, const float* addsrc,
    const int* __restrict__ rowidx, const int* __restrict__ counts,
    const int* __restrict__ offsets,
    int M, int N, int K, int lda, int ldb, int ldc, long bstride)
{
    __shared__ __align__(16) unsigned short As[SPLIT][128*32];
    __shared__ __align__(16) unsigned short Bs[SPLIT][128*32];

    int off = 0, Mloc = M;
    const float* Bp = Bmat;
    if (GROUPED) {
        int e = blockIdx.z;
        Mloc = counts[e];
        off  = offsets[e];
        Bp   = Bmat + (long)e * bstride;
    }
    int bx = SWAP ? blockIdx.y : blockIdx.x;
    int by = SWAP ? blockIdx.x : blockIdx.y;
    int n0 = bx * 128;
    int m0 = by * 128;
    if (m0 >= Mloc) return;

    int tid = threadIdx.x;
    int w = tid >> 6, lane = tid & 63;
    int wm = (w >> 1) << 6, wn = (w & 1) << 6;
    int lr = lane & 15, lg = lane >> 4;

    f32x4 zero = {0.f, 0.f, 0.f, 0.f};
    f32x4 acc[4][4];
    #pragma unroll
    for (int mi = 0; mi < 4; mi++)
        #pragma unroll
        for (int ni = 0; ni < 4; ni++)
            acc[mi][ni] = zero;

    int ar  = tid >> 3;          // 0..31
    int ac  = (tid & 7) << 2;    // 0..28
    int bkk = tid >> 5;          // 0..7
    int bc  = (tid & 31) << 2;   // 0..124

    for (int k0 = 0; k0 < K; k0 += 32) {
        // stage A (128 x 32)
        #pragma unroll
        for (int p = 0; p < 4; p++) {
            int r = p*32 + ar;
            f32x4 vv = zero;
            if (m0 + r < Mloc) {
                long arow;
                if (GROUPED) arow = GATHER ? (long)rowidx[off + m0 + r] : (long)(off + m0 + r);
                else         arow = m0 + r;
                vv = *(const f32x4*)(A + arow * (long)lda + k0 + ac);
            }
            if (SPLIT == 3) {
                u16x4 hv, mv, lv;
                #pragma unroll
                for (int jj = 0; jj < 4; jj++) { unsigned short h,m,l; split3(vv[jj],h,m,l); hv[jj]=h; mv[jj]=m; lv[jj]=l; }
                *(u16x4*)&As[0][r*32 + ac] = hv;
                *(u16x4*)&As[1][r*32 + ac] = mv;
                *(u16x4*)&As[2][r*32 + ac] = lv;
            } else {
                unsigned short* d = &As[0][r*32 + ac];
                d[0]=f2bf(vv.x); d[1]=f2bf(vv.y); d[2]=f2bf(vv.z); d[3]=f2bf(vv.w);
            }
        }
        // stage B
        if (BT) {
            #pragma unroll
            for (int p = 0; p < 4; p++) {
                int r = p*32 + ar;
                f32x4 vv = *(const f32x4*)(Bp + (long)(n0 + r) * ldb + k0 + ac);
                if (SPLIT == 3) {
                    u16x4 hv, mv, lv;
                    #pragma unroll
                    for (int jj = 0; jj < 4; jj++) { unsigned short h,m,l; split3(vv[jj],h,m,l); hv[jj]=h; mv[jj]=m; lv[jj]=l; }
                    *(u16x4*)&Bs[0][r*32 + ac] = hv;
                    *(u16x4*)&Bs[1][r*32 + ac] = mv;
                    *(u16x4*)&Bs[2][r*32 + ac] = lv;
                } else {
                    unsigned short* d = &Bs[0][r*32 + ac];
                    d[0]=f2bf(vv.x); d[1]=f2bf(vv.y); d[2]=f2bf(vv.z); d[3]=f2bf(vv.w);
                }
            }
        } else {
            #pragma unroll
            for (int p = 0; p < 4; p++) {
                int kk = p*8 + bkk;
                f32x4 vv = *(const f32x4*)(Bp + (long)(k0 + kk) * ldb + n0 + bc);
                if (SPLIT == 3) {
                    #pragma unroll
                    for (int jj = 0; jj < 4; jj++) {
                        unsigned short h,m,l; split3(vv[jj],h,m,l);
                        Bs[0][(bc+jj)*32 + kk] = h;
                        Bs[1][(bc+jj)*32 + kk] = m;
                        Bs[2][(bc+jj)*32 + kk] = l;
                    }
                } else {
                    Bs[0][(bc+0)*32 + kk] = f2bf(vv.x);
                    Bs[0][(bc+1)*32 + kk] = f2bf(vv.y);
                    Bs[0][(bc+2)*32 + kk] = f2bf(vv.z);
                    Bs[0][(bc+3)*32 + kk] = f2bf(vv.w);
                }
            }
        }
        __syncthreads();

        bf16x8 af[SPLIT][4], bfv[SPLIT][4];
        #pragma unroll
        for (int s = 0; s < SPLIT; s++) {
            #pragma unroll
            for (int mi = 0; mi < 4; mi++)
                af[s][mi] = *(const bf16x8*)&As[s][(wm + mi*16 + lr)*32 + lg*8];
            #pragma unroll
            for (int ni = 0; ni < 4; ni++)
                bfv[s][ni] = *(const bf16x8*)&Bs[s][(wn + ni*16 + lr)*32 + lg*8];
        }
        #pragma unroll
        for (int mi = 0; mi < 4; mi++)
            #pragma unroll
            for (int ni = 0; ni < 4; ni++) {
                acc[mi][ni] = MFMA(af[0][mi], bfv[0][ni], acc[mi][ni]);
                if (SPLIT == 3) {
                    acc[mi][ni] = MFMA(af[0][mi], bfv[1][ni], acc[mi][ni]);
                    acc[mi][ni] = MFMA(af[1][mi], bfv[0][ni], acc[mi][ni]);
                    acc[mi][ni] = MFMA(af[0][mi], bfv[2][ni], acc[mi][ni]);
                    acc[mi][ni] = MFMA(af[1][mi], bfv[1][ni], acc[mi][ni]);
                    acc[mi][ni] = MFMA(af[2][mi], bfv[0][ni], acc[mi][ni]);
                }
            }
        __syncthreads();
    }

    #pragma unroll
    for (int mi = 0; mi < 4; mi++) {
        #pragma unroll
        for (int r = 0; r < 4; r++) {
            int rowl = wm + mi*16 + lg*4 + r;
            if (m0 + rowl < Mloc) {
                long crow = GROUPED ? (long)(off + m0 + rowl) : (long)(m0 + rowl);
                #pragma unroll
                for (int ni = 0; ni < 4; ni++) {
                    int col = n0 + wn + ni*16 + lr;
                    float val = acc[mi][ni][r];
                    if (EPI == 1) val += addsrc[crow * (long)ldc + col];
                    C[crow * (long)ldc + col] = val;
                }
            }
        }
    }
}

// ---------------- fused MoE w1/w3 grouped GEMM (split-bf16): g = silu(A@w1)*(A@w3), f32 out ----------------
__global__ __launch_bounds__(256) void moe13_kernel(
    const float* __restrict__ A, const float* __restrict__ W1,
    const float* __restrict__ W3, float* __restrict__ G,
    const int* __restrict__ rowidx, const int* __restrict__ counts,
    const int* __restrict__ offsets)
{
    __shared__ __align__(16) unsigned short As[3][128*32];
    __shared__ __align__(16) unsigned short B1s[3][128*32];
    __shared__ __align__(16) unsigned short B3s[3][128*32];

    int e = blockIdx.z;
    int cnt = counts[e], off = offsets[e];
    int n0 = blockIdx.x * 128;
    int m0 = blockIdx.y * 128;
    if (m0 >= cnt) return;
    const float* b1p = W1 + (long)e * (D_MODEL*FFH);
    const float* b3p = W3 + (long)e * (D_MODEL*FFH);

    int tid = threadIdx.x;
    int w = tid >> 6, lane = tid & 63;
    int wm = (w >> 1) << 6, wn = (w & 1) << 6;
    int lr = lane & 15, lg = lane >> 4;

    f32x4 zero = {0.f,0.f,0.f,0.f};
    f32x4 a1[4][4], a3[4][4];
    #pragma unroll
    for (int mi = 0; mi < 4; mi++)
        #pragma unroll
        for (int ni = 0; ni < 4; ni++) { a1[mi][ni] = zero; a3[mi][ni] = zero; }

    int ar  = tid >> 3, ac = (tid & 7) << 2;
    int bkk = tid >> 5, bc = (tid & 31) << 2;

    for (int k0 = 0; k0 < D_MODEL; k0 += 32) {
        #pragma unroll
        for (int p = 0; p < 4; p++) {
            int r = p*32 + ar;
            f32x4 vv = zero;
            if (m0 + r < cnt) {
                long arow = (long)rowidx[off + m0 + r];
                vv = *(const f32x4*)(A + arow * (long)D_MODEL + k0 + ac);
            }
            u16x4 hv, mv, lv;
            #pragma unroll
            for (int jj = 0; jj < 4; jj++) { unsigned short h,m,l; split3(vv[jj],h,m,l); hv[jj]=h; mv[jj]=m; lv[jj]=l; }
            *(u16x4*)&As[0][r*32 + ac] = hv;
            *(u16x4*)&As[1][r*32 + ac] = mv;
            *(u16x4*)&As[2][r*32 + ac] = lv;
        }
        #pragma unroll
        for (int p = 0; p < 4; p++) {
            int kk = p*8 + bkk;
            f32x4 v1 = *(const f32x4*)(b1p + (long)(k0 + kk) * FFH + n0 + bc);
            f32x4 v3 = *(const f32x4*)(b3p + (long)(k0 + kk) * FFH + n0 + bc);
            #pragma unroll
            for (int jj = 0; jj < 4; jj++) {
                unsigned short h,m,l;
                split3(v1[jj],h,m,l);
                B1s[0][(bc+jj)*32 + kk] = h; B1s[1][(bc+jj)*32 + kk] = m; B1s[2][(bc+jj)*32 + kk] = l;
                split3(v3[jj],h,m,l);
                B3s[0][(bc+jj)*32 + kk] = h; B3s[1][(bc+jj)*32 + kk] = m; B3s[2][(bc+jj)*32 + kk] = l;
            }
        }
        __syncthreads();

        bf16x8 af[3][4], f1[3][4], f3[3][4];
        #pragma unroll
        for (int s = 0; s < 3; s++) {
            #pragma unroll
            for (int mi = 0; mi < 4; mi++)
                af[s][mi] = *(const bf16x8*)&As[s][(wm + mi*16 + lr)*32 + lg*8];
            #pragma unroll
            for (int ni = 0; ni < 4; ni++) {
                f1[s][ni] = *(const bf16x8*)&B1s[s][(wn + ni*16 + lr)*32 + lg*8];
                f3[s][ni] = *(const bf16x8*)&B3s[s][(wn + ni*16 + lr)*32 + lg*8];
            }
        }
        #pragma unroll
        for (int mi = 0; mi < 4; mi++)
            #pragma unroll
            for (int ni = 0; ni < 4; ni++) {
                a1[mi][ni] = MFMA(af[0][mi], f1[0][ni], a1[mi][ni]);
                a1[mi][ni] = MFMA(af[0][mi], f1[1][ni], a1[mi][ni]);
                a1[mi][ni] = MFMA(af[1][mi], f1[0][ni], a1[mi][ni]);
                a1[mi][ni] = MFMA(af[0][mi], f1[2][ni], a1[mi][ni]);
                a1[mi][ni] = MFMA(af[1][mi], f1[1][ni], a1[mi][ni]);
                a1[mi][ni] = MFMA(af[2][mi], f1[0][ni], a1[mi][ni]);
                a3[mi][ni] = MFMA(af[0][mi], f3[0][ni], a3[mi][ni]);
                a3[mi][ni] = MFMA(af[0][mi], f3[1][ni], a3[mi][ni]);
                a3[mi][ni] = MFMA(af[1][mi], f3[0][ni], a3[mi][ni]);
                a3[mi][ni] = MFMA(af[0][mi], f3[2][ni], a3[mi][ni]);
                a3[mi][ni] = MFMA(af[1][mi], f3[1][ni], a3[mi][ni]);
                a3[mi][ni] = MFMA(af[2][mi], f3[0][ni], a3[mi][ni]);
            }
        __syncthreads();
    }

    #pragma unroll
    for (int mi = 0; mi < 4; mi++) {
        #pragma unroll
        for (int r = 0; r < 4; r++) {
            int rowl = wm + mi*16 + lg*4 + r;
            if (m0 + rowl < cnt) {
                long crow = off + m0 + rowl;
                #pragma unroll
                for (int ni = 0; ni < 4; ni++) {
                    int col = n0 + wn + ni*16 + lr;
                    float v1 = a1[mi][ni][r];
                    float v3 = a3[mi][ni][r];
                    float sl = v1 / (1.f + expf(-v1));
                    G[crow * (long)FFH + col] = sl * v3;
                }
            }
        }
    }
}

// ---------------- flash attention (causal, split-bf16, 32-wide KV tiles) ----------------
__global__ __launch_bounds__(256) void attn_kernel(
    const float* __restrict__ q, const float* __restrict__ k,
    const float* __restrict__ v, float* __restrict__ att)
{
    // Q: [64 rows][72], K: [32 rows][72] (reused for P: [64 rows][40]), V^T: [64 dims][40]
    __shared__ __align__(16) unsigned short Qs[3][64*72];
    __shared__ __align__(16) unsigned short KP[3][2560];
    __shared__ __align__(16) unsigned short Vt[3][2560];

    int qt = blockIdx.x, bh = blockIdx.y;
    int b = bh >> 4, hh = bh & 15;
    int tid = threadIdx.x, w = tid >> 6, lane = tid & 63;
    int lr = lane & 15, lg = lane >> 4;
    int lrow = tid >> 4;           // 0..15
    int lcol = (tid & 15) << 2;    // 0..60

    const float* qbase = q + ((long)(b*SEQ + qt*64) * D_MODEL + hh*64);
    #pragma unroll
    for (int p = 0; p < 4; p++) {
        int r = p*16 + lrow;
        f32x4 vv = *(const f32x4*)(qbase + (long)r * D_MODEL + lcol);
        #pragma unroll
        for (int jj = 0; jj < 4; jj++) {
            unsigned short h,m,l; split3(vv[jj],h,m,l);
            Qs[0][r*72 + lcol + jj] = h;
            Qs[1][r*72 + lcol + jj] = m;
            Qs[2][r*72 + lcol + jj] = l;
        }
    }

    f32x4 zero = {0.f,0.f,0.f,0.f};
    f32x4 oacc[4] = {zero, zero, zero, zero};
    float mrun[4] = {-INFINITY,-INFINITY,-INFINITY,-INFINITY};
    float lrun[4] = {0.f,0.f,0.f,0.f};

    int ntile = 2*qt + 2;
    for (int jt = 0; jt < ntile; jt++) {
        const float* kbase = k + ((long)(b*SEQ + jt*32) * D_MODEL + hh*64);
        const float* vbase = v + ((long)(b*SEQ + jt*32) * D_MODEL + hh*64);
        #pragma unroll
        for (int p = 0; p < 2; p++) {
            int r = p*16 + lrow;
            f32x4 kv4 = *(const f32x4*)(kbase + (long)r * D_MODEL + lcol);
            f32x4 vv4 = *(const f32x4*)(vbase + (long)r * D_MODEL + lcol);
            #pragma unroll
            for (int jj = 0; jj < 4; jj++) {
                unsigned short h,m,l;
                split3(kv4[jj],h,m,l);
                KP[0][r*72 + lcol + jj] = h;
                KP[1][r*72 + lcol + jj] = m;
                KP[2][r*72 + lcol + jj] = l;
                split3(vv4[jj],h,m,l);
                Vt[0][(lcol+jj)*40 + r] = h;
                Vt[1][(lcol+jj)*40 + r] = m;
                Vt[2][(lcol+jj)*40 + r] = l;
            }
        }
        __syncthreads();

        // S = Q K^T (this wave's 16 q-rows x 32 k-cols)
        f32x4 s[2] = {zero, zero};
        #pragma unroll
        for (int ks = 0; ks < 2; ks++) {
            bf16x8 qh = *(const bf16x8*)&Qs[0][(w*16 + lr)*72 + ks*32 + lg*8];
            bf16x8 qm = *(const bf16x8*)&Qs[1][(w*16 + lr)*72 + ks*32 + lg*8];
            bf16x8 ql = *(const bf16x8*)&Qs[2][(w*16 + lr)*72 + ks*32 + lg*8];
            #pragma unroll
            for (int ni = 0; ni < 2; ni++) {
                bf16x8 kh = *(const bf16x8*)&KP[0][(ni*16 + lr)*72 + ks*32 + lg*8];
                bf16x8 km = *(const bf16x8*)&KP[1][(ni*16 + lr)*72 + ks*32 + lg*8];
                bf16x8 kl = *(const bf16x8*)&KP[2][(ni*16 + lr)*72 + ks*32 + lg*8];
                s[ni] = MFMA(qh, kh, s[ni]);
                s[ni] = MFMA(qh, km, s[ni]);
                s[ni] = MFMA(qm, kh, s[ni]);
                s[ni] = MFMA(qh, kl, s[ni]);
                s[ni] = MFMA(qm, km, s[ni]);
                s[ni] = MFMA(ql, kh, s[ni]);
            }
        }
        __syncthreads();   // all waves done reading KP as K

        // online softmax + write P (split) into KP planes, layout [q][40]
        #pragma unroll
        for (int r = 0; r < 4; r++) {
            int qg = qt*64 + w*16 + lg*4 + r;
            float mx = -INFINITY;
            #pragma unroll
            for (int ni = 0; ni < 2; ni++) {
                int kg = jt*32 + ni*16 + lr;
                float val = s[ni][r] * 0.125f;
                if (kg > qg) val = -INFINITY;
                s[ni][r] = val;
                mx = fmaxf(mx, val);
            }
            #pragma unroll
            for (int dd = 1; dd < 16; dd <<= 1)
                mx = fmaxf(mx, __shfl_xor(mx, dd));
            float mnew  = fmaxf(mrun[r], mx);
            float alpha = expf(mrun[r] - mnew);
            float ps = 0.f;
            #pragma unroll
            for (int ni = 0; ni < 2; ni++) {
                float pv = expf(s[ni][r] - mnew);
                s[ni][r] = pv;
                ps += pv;
            }
            #pragma unroll
            for (int dd = 1; dd < 16; dd <<= 1)
                ps += __shfl_xor(ps, dd);
            lrun[r] = lrun[r] * alpha + ps;
            mrun[r] = mnew;
            #pragma unroll
            for (int d = 0; d < 4; d++) oacc[d][r] *= alpha;
            int prow = w*16 + lg*4 + r;
            #pragma unroll
            for (int ni = 0; ni < 2; ni++) {
                unsigned short h,m,l; split3(s[ni][r],h,m,l);
                KP[0][prow*40 + ni*16 + lr] = h;
                KP[1][prow*40 + ni*16 + lr] = m;
                KP[2][prow*40 + ni*16 + lr] = l;
            }
        }

        // O += P @ V  (wave-private P rows; within-wave LDS ordering)
        {
            bf16x8 ph = *(const bf16x8*)&KP[0][(w*16 + lr)*40 + lg*8];
            bf16x8 pm = *(const bf16x8*)&KP[1][(w*16 + lr)*40 + lg*8];
            bf16x8 pl = *(const bf16x8*)&KP[2][(w*16 + lr)*40 + lg*8];
            #pragma unroll
            for (int ni = 0; ni < 4; ni++) {
                bf16x8 vh = *(const bf16x8*)&Vt[0][(ni*16 + lr)*40 + lg*8];
                bf16x8 vm = *(const bf16x8*)&Vt[1][(ni*16 + lr)*40 + lg*8];
                bf16x8 vl = *(const bf16x8*)&Vt[2][(ni*16 + lr)*40 + lg*8];
                oacc[ni] = MFMA(ph, vh, oacc[ni]);
                oacc[ni] = MFMA(ph, vm, oacc[ni]);
                oacc[ni] = MFMA(pm, vh, oacc[ni]);
                oacc[ni] = MFMA(ph, vl, oacc[ni]);
                oacc[ni] = MFMA(pm, vm, oacc[ni]);
                oacc[ni] = MFMA(pl, vh, oacc[ni]);
            }
        }
        __syncthreads();
    }

    float* obase = att + ((long)(b*SEQ + qt*64) * D_MODEL + hh*64);
    #pragma unroll
    for (int r = 0; r < 4; r++) {
        float inv = 1.f / lrun[r];
        #pragma unroll
        for (int ni = 0; ni < 4; ni++)
            obase[(long)(w*16 + lg*4 + r) * D_MODEL + ni*16 + lr] = oacc[ni][r] * inv;
    }
}

// ---------------- small kernels ----------------
__global__ __launch_bounds__(256) void embed_kernel(const int* __restrict__ tok,
    const float* __restrict__ emb, float* __restrict__ h)
{
    int n = blockIdx.x;
    int c = threadIdx.x << 2;
    long t = tok[n];
    *(f32x4*)(h + (long)n*D_MODEL + c) = *(const f32x4*)(emb + t*D_MODEL + c);
}

__global__ __launch_bounds__(256) void rmsnorm_kernel(const float* __restrict__ x,
    const float* __restrict__ wt, float* __restrict__ out)
{
    __shared__ float red[4];
    int n = blockIdx.x;
    int c = threadIdx.x << 2;
    f32x4 v = *(const f32x4*)(x + (long)n*D_MODEL + c);
    float ss = v.x*v.x + v.y*v.y + v.z*v.z + v.w*v.w;
    #pragma unroll
    for (int dd = 32; dd; dd >>= 1) ss += __shfl_xor(ss, dd);
    if ((threadIdx.x & 63) == 0) red[threadIdx.x >> 6] = ss;
    __syncthreads();
    float tot = red[0] + red[1] + red[2] + red[3];
    float rms = rsqrtf(tot * (1.f / D_MODEL) + 1e-6f);
    f32x4 wv = *(const f32x4*)(wt + c);
    f32x4 o = v * rms;
    o = o * wv;
    *(f32x4*)(out + (long)n*D_MODEL + c) = o;
}

__global__ __launch_bounds__(256) void rope_kernel(float* __restrict__ q, float* __restrict__ kk)
{
    int gid = blockIdx.x * 256 + threadIdx.x;
    if (gid >= NTOK * 512) return;
    int n   = gid >> 9;
    int rem = gid & 511;
    int hh  = rem >> 5;
    int i   = rem & 31;
    int t   = n & (SEQ - 1);
    double inv = pow(10000.0, -(double)(2*i) / 64.0);
    double ang = (double)t * inv;
    double sn = sin(ang), cs = cos(ang);
    long base = (long)n * D_MODEL + hh*64 + 2*i;
    double qr = q[base], qi = q[base+1];
    q[base]   = (float)(qr*cs - qi*sn);
    q[base+1] = (float)(qr*sn + qi*cs);
    double kr = kk[base], ki = kk[base+1];
    kk[base]   = (float)(kr*cs - ki*sn);
    kk[base+1] = (float)(kr*sn + ki*cs);
}

__global__ __launch_bounds__(64) void gate_kernel(const float* __restrict__ xf,
    const float* __restrict__ gw, int* __restrict__ counts,
    int* __restrict__ eid, float* __restrict__ wts, float* __restrict__ pbuf)
{
    int n = blockIdx.x;
    int lane = threadIdx.x;
    float acc[8] = {0,0,0,0,0,0,0,0};
    const float* xr = xf + (long)n * D_MODEL;
    for (int d = lane; d < D_MODEL; d += 64) {
        float xv = xr[d];
        const float* g = gw + d * 8;
        #pragma unroll
        for (int e = 0; e < 8; e++) acc[e] += xv * g[e];
    }
    #pragma unroll
    for (int e = 0; e < 8; e++) {
        #pragma unroll
        for (int dd = 32; dd; dd >>= 1) acc[e] += __shfl_xor(acc[e], dd);
    }
    if (lane == 0) {
        float mx = acc[0];
        #pragma unroll
        for (int e = 1; e < 8; e++) mx = fmaxf(mx, acc[e]);
        float pe[8], ssum = 0.f;
        #pragma unroll
        for (int e = 0; e < 8; e++) { pe[e] = expf(acc[e] - mx); ssum += pe[e]; }
        float sinv = 1.f / ssum;
        #pragma unroll
        for (int e = 0; e < 8; e++) { pe[e] *= sinv; pbuf[n*8 + e] = pe[e]; }
        int e1 = 0;
        #pragma unroll
        for (int e = 1; e < 8; e++) if (pe[e] > pe[e1]) e1 = e;
        int e2 = -1;
        #pragma unroll
        for (int e = 0; e < 8; e++) if (e != e1 && (e2 < 0 || pe[e] > pe[e2])) e2 = e;
        float v1 = pe[e1], v2 = pe[e2];
        float wsum = v1 + v2 + 1e-8f;
        eid[n*2] = e1; eid[n*2+1] = e2;
        wts[n*2] = v1 / wsum; wts[n*2+1] = v2 / wsum;
        atomicAdd(counts + e1, 1);
        atomicAdd(counts + e2, 1);
    }
}

__global__ __launch_bounds__(64) void scan_kernel(const int* __restrict__ counts,
    int* __restrict__ offs, int* __restrict__ cursor,
    const float* __restrict__ pbuf, float* __restrict__ aux)
{
    __shared__ float red[8];
    int t = threadIdx.x;
    if (t < 8) {
        float s = 0.f;
        for (int n = 0; n < NTOK; n++) s += pbuf[n*8 + t];
        red[t] = s;
    }
    __syncthreads();
    if (t == 0) {
        int o = 0; float a = 0.f;
        for (int e = 0; e < 8; e++) {
            offs[e] = o; cursor[e] = o; o += counts[e];
            a += (float)counts[e] * red[e];
        }
        aux[0] += 8.f * a / ((float)NTOK * (float)NTOK);
    }
}

__global__ __launch_bounds__(256) void assign_kernel(const int* __restrict__ eid,
    int* __restrict__ cursor, int* __restrict__ rowidx, int* __restrict__ tpos)
{
    int n = blockIdx.x * 256 + threadIdx.x;
    if (n >= NTOK) return;
    #pragma unroll
    for (int s = 0; s < 2; s++) {
        int e = eid[n*2 + s];
        int p = atomicAdd(cursor + e, 1);
        rowidx[p] = n;
        tpos[n*2 + s] = p;
    }
}

__global__ __launch_bounds__(256) void combine_kernel(
    float* __restrict__ h, const float* __restrict__ eob,
    const int* __restrict__ tpos, const float* __restrict__ wts)
{
    int n = blockIdx.x;
    int c = threadIdx.x << 2;
    int p0 = tpos[n*2], p1 = tpos[n*2+1];
    float w0 = wts[n*2], w1 = wts[n*2+1];
    f32x4 hv = *(const f32x4*)(h   + (long)n  * D_MODEL + c);
    f32x4 e0 = *(const f32x4*)(eob + (long)p0 * D_MODEL + c);
    f32x4 e1 = *(const f32x4*)(eob + (long)p1 * D_MODEL + c);
    hv = hv + w0 * e0 + w1 * e1;
    *(f32x4*)(h + (long)n * D_MODEL + c) = hv;
}

__global__ void write_aux_kernel(float* __restrict__ out, const float* __restrict__ aux)
{
    if (threadIdx.x == 0 && blockIdx.x == 0)
        out[(long)NTOK * VOCAB] = aux[0];
}

// ---------------- launch ----------------
extern "C" void kernel_launch(void* const* d_in, const int* in_sizes, int n_in,
                              void* d_out, int out_size, void* d_ws, size_t ws_size,
                              hipStream_t stream)
{
    const int*   tokens = (const int*)d_in[0];
    const float* emb    = (const float*)d_in[1];
    const float* anw    = (const float*)d_in[2];
    const float* wq     = (const float*)d_in[3];
    const float* wk     = (const float*)d_in[4];
    const float* wv     = (const float*)d_in[5];
    const float* wo     = (const float*)d_in[6];
    const float* fnw    = (const float*)d_in[7];
    const float* gw     = (const float*)d_in[8];
    const float* w1     = (const float*)d_in[9];
    const float* w2     = (const float*)d_in[10];
    const float* w3     = (const float*)d_in[11];
    const float* finw   = (const float*)d_in[12];
    float* out = (float*)d_out;

    char* W = (char*)d_ws;
    const size_t MB = 1024u * 1024u;
    int*   counts = (int*)(W + 0);
    int*   offs   = (int*)(W + 32);
    int*   cursor = (int*)(W + 64);
    float* aux    = (float*)(W + 96);
    int*   eid    = (int*)(W + 1024);
    int*   tpos   = (int*)(W + 1024 + 16384);
    float* wts    = (float*)(W + 1024 + 32768);
    int*   rowix  = (int*)(W + 1024 + 49152);
    float* pbuf   = (float*)(W + 1024 + 65536);
    float* h    = (float*)(W + 1*MB);
    float* hn   = (float*)(W + 9*MB);
    float* qb   = (float*)(W + 17*MB);
    float* kb   = (float*)(W + 25*MB);
    float* vb   = (float*)(W + 33*MB);
    float* att  = (float*)(W + 41*MB);
    float* g    = (float*)(W + 17*MB);   // MoE phase: overlaps qb/kb/vb/att (dead)
    float* eob  = (float*)(W + 49*MB);

    hipMemsetAsync(W, 0, 100, stream);   // counts/offs/cursor/aux
    embed_kernel<<<NTOK, 256, 0, stream>>>(tokens, emb, h);

    for (int l = 0; l < 2; l++) {
        rmsnorm_kernel<<<NTOK, 256, 0, stream>>>(h, anw + (size_t)l*D_MODEL, hn);

        dim3 gqkv(D_MODEL/128, NTOK/128);
        const float* wql = wq + (size_t)l*D_MODEL*D_MODEL;
        const float* wkl = wk + (size_t)l*D_MODEL*D_MODEL;
        const float* wvl = wv + (size_t)l*D_MODEL*D_MODEL;
        const float* wol = wo + (size_t)l*D_MODEL*D_MODEL;
        gemm_kernel<3,0,0,0,0,0><<<gqkv, 256, 0, stream>>>(hn, wql, qb, nullptr, nullptr, nullptr, nullptr,
            NTOK, D_MODEL, D_MODEL, D_MODEL, D_MODEL, D_MODEL, 0);
        gemm_kernel<3,0,0,0,0,0><<<gqkv, 256, 0, stream>>>(hn, wkl, kb, nullptr, nullptr, nullptr, nullptr,
            NTOK, D_MODEL, D_MODEL, D_MODEL, D_MODEL, D_MODEL, 0);
        gemm_kernel<3,0,0,0,0,0><<<gqkv, 256, 0, stream>>>(hn, wvl, vb, nullptr, nullptr, nullptr, nullptr,
            NTOK, D_MODEL, D_MODEL, D_MODEL, D_MODEL, D_MODEL, 0);

        rope_kernel<<<(NTOK*512 + 255)/256, 256, 0, stream>>>(qb, kb);

        attn_kernel<<<dim3(SEQ/64, BATCH*NHEADS), 256, 0, stream>>>(qb, kb, vb, att);

        gemm_kernel<3,0,1,0,0,0><<<gqkv, 256, 0, stream>>>(att, wol, h, h, nullptr, nullptr, nullptr,
            NTOK, D_MODEL, D_MODEL, D_MODEL, D_MODEL, D_MODEL, 0);

        rmsnorm_kernel<<<NTOK, 256, 0, stream>>>(h, fnw + (size_t)l*D_MODEL, hn);

        hipMemsetAsync(W, 0, 96, stream);   // counts/offs/cursor (keeps aux)
        gate_kernel<<<NTOK, 64, 0, stream>>>(hn, gw + (size_t)l*D_MODEL*NEXP, counts, eid, wts, pbuf);
        scan_kernel<<<1, 64, 0, stream>>>(counts, offs, cursor, pbuf, aux);
        assign_kernel<<<(NTOK + 255)/256, 256, 0, stream>>>(eid, cursor, rowix, tpos);

        dim3 g13(FFH/128, NTOK/128, NEXP);
        const float* w1l = w1 + (size_t)l*NEXP*D_MODEL*FFH;
        const float* w3l = w3 + (size_t)l*NEXP*D_MODEL*FFH;
        const float* w2l = w2 + (size_t)l*NEXP*FFH*D_MODEL;
        moe13_kernel<<<g13, 256, 0, stream>>>(hn, w1l, w3l, g, rowix, counts, offs);

        dim3 g2(D_MODEL/128, NTOK/128, NEXP);
        gemm_kernel<3,0,0,1,0,0><<<g2, 256, 0, stream>>>(g, w2l, eob, nullptr, rowix, counts, offs,
            NTOK, D_MODEL, FFH, FFH, D_MODEL, D_MODEL, (long)FFH*D_MODEL);

        combine_kernel<<<NTOK, 256, 0, stream>>>(h, eob, tpos, wts);
    }

    rmsnorm_kernel<<<NTOK, 256, 0, stream>>>(h, finw, hn);
    gemm_kernel<1,1,0,0,0,1><<<dim3(NTOK/128, VOCAB/128), 256, 0, stream>>>(hn, emb, out,
        nullptr, nullptr, nullptr, nullptr, NTOK, VOCAB, D_MODEL, D_MODEL, D_MODEL, VOCAB, 0);
    write_aux_kernel<<<1, 1, 0, stream>>>(out, aux);
}

// Round 4
// 2675.037 us; speedup vs baseline: 2.7837x; 2.7837x over previous
//
#include <hip/hip_runtime.h>
#include <hip/hip_bf16.h>
#include <math.h>

#define D_MODEL 1024
#define NHEADS  16
#define HDIM    64
#define NEXP    8
#define FFH     2048
#define BATCH   2
#define SEQ     1024
#define NTOK    2048
#define VOCAB   32000
#define LDSS    40   // LDS row stride in shorts (80 B: 16B-aligned, 20 dwords -> conflict-free reads)

typedef __attribute__((ext_vector_type(4))) float f32x4;
typedef __attribute__((ext_vector_type(8))) __bf16 bf16x8;
typedef __attribute__((ext_vector_type(4))) unsigned short u16x4;

__device__ __forceinline__ unsigned short f2bf(float f) {
    union { float f; unsigned u; } v; v.f = f;
    unsigned r = v.u + 0x7FFFu + ((v.u >> 16) & 1u);
    return (unsigned short)(r >> 16);
}
__device__ __forceinline__ float bf2f(unsigned short u) {
    union { unsigned u; float f; } v; v.u = ((unsigned)u) << 16; return v.f;
}
__device__ __forceinline__ void split3(float x, unsigned short& h, unsigned short& m, unsigned short& l) {
    h = f2bf(x);
    float r1 = x - bf2f(h);
    m = f2bf(r1);
    float r2 = r1 - bf2f(m);
    l = f2bf(r2);
}

#define MFMA(a, b, c) __builtin_amdgcn_mfma_f32_16x16x32_bf16((a), (b), (c), 0, 0, 0)

// ---------------- split-bf16 MFMA GEMM ----------------
// C[M,N] = A[M,K] @ B[K,N], f32 in/out.
// SPLIT: 1 = plain bf16, 3 = hi/mid/lo (6 products, f32-accurate)
// BT: B stored N-major (NxK). EPI: 0 none, 1 C=acc+addsrc, 2 C=silu(addsrc)*acc.
// GROUPED: blockIdx.z = expert. GATHER: A row via rowidx. SWAP: swap bx/by.
// MULTI: blockIdx.z selects B0/B1/B2, C += z*M*ldc (fused QKV).
template<int SPLIT, int BT, int EPI, int GROUPED, int GATHER, int SWAP, int MULTI>
__global__ __launch_bounds__(256) void gemm_kernel(
    const float* __restrict__ A, const float* __restrict__ B0,
    const float* __restrict__ B1, const float* __restrict__ B2,
    float* C, const float* addsrc,
    const int* __restrict__ rowidx, const int* __restrict__ counts,
    const int* __restrict__ offsets,
    int M, int N, int K, int lda, int ldb, int ldc, long bstride)
{
    __shared__ __align__(16) unsigned short As[SPLIT][128*LDSS];
    __shared__ __align__(16) unsigned short Bs[SPLIT][128*LDSS];

    int off = 0, Mloc = M;
    const float* Bp = B0;
    long cbase = 0;
    if (GROUPED) {
        int e = blockIdx.z;
        Mloc = counts[e];
        off  = offsets[e];
        Bp   = B0 + (long)e * bstride;
    }
    if (MULTI) {
        int z = blockIdx.z;
        Bp = (z == 0) ? B0 : (z == 1) ? B1 : B2;
        cbase = (long)z * (long)M * ldc;
    }
    int bx = SWAP ? blockIdx.y : blockIdx.x;
    int by = SWAP ? blockIdx.x : blockIdx.y;
    int n0 = bx * 128;
    int m0 = by * 128;
    if (m0 >= Mloc) return;

    int tid = threadIdx.x;
    int w = tid >> 6, lane = tid & 63;
    int wm = (w >> 1) << 6, wn = (w & 1) << 6;
    int lr = lane & 15, lg = lane >> 4;

    f32x4 zero = {0.f, 0.f, 0.f, 0.f};
    f32x4 acc[4][4];
    #pragma unroll
    for (int mi = 0; mi < 4; mi++)
        #pragma unroll
        for (int ni = 0; ni < 4; ni++)
            acc[mi][ni] = zero;

    int rb = tid >> 3;           // 0..31
    int kc = (tid & 7) << 2;     // 0..28

    for (int k0 = 0; k0 < K; k0 += 32) {
        // ---- stage A: rows p*32+rb, k-chunk kc (vector loads+writes)
        #pragma unroll
        for (int p = 0; p < 4; p++) {
            int r = p*32 + rb;
            f32x4 vv = zero;
            if (!GROUPED || (m0 + r < Mloc)) {
                long arow;
                if (GROUPED) arow = GATHER ? (long)rowidx[off + m0 + r] : (long)(off + m0 + r);
                else         arow = m0 + r;
                vv = *(const f32x4*)(A + arow * (long)lda + k0 + kc);
            }
            if (SPLIT == 3) {
                u16x4 hv, mv, lv;
                #pragma unroll
                for (int j = 0; j < 4; j++) { unsigned short h,m,l; split3(vv[j],h,m,l); hv[j]=h; mv[j]=m; lv[j]=l; }
                *(u16x4*)&As[0][r*LDSS + kc] = hv;
                *(u16x4*)&As[1][r*LDSS + kc] = mv;
                *(u16x4*)&As[2][r*LDSS + kc] = lv;
            } else {
                u16x4 hv;
                #pragma unroll
                for (int j = 0; j < 4; j++) hv[j] = f2bf(vv[j]);
                *(u16x4*)&As[0][r*LDSS + kc] = hv;
            }
        }
        // ---- stage B
        if (BT) {
            #pragma unroll
            for (int p = 0; p < 4; p++) {
                int r = p*32 + rb;
                f32x4 vv = *(const f32x4*)(Bp + (long)(n0 + r) * ldb + k0 + kc);
                if (SPLIT == 3) {
                    u16x4 hv, mv, lv;
                    #pragma unroll
                    for (int j = 0; j < 4; j++) { unsigned short h,m,l; split3(vv[j],h,m,l); hv[j]=h; mv[j]=m; lv[j]=l; }
                    *(u16x4*)&Bs[0][r*LDSS + kc] = hv;
                    *(u16x4*)&Bs[1][r*LDSS + kc] = mv;
                    *(u16x4*)&Bs[2][r*LDSS + kc] = lv;
                } else {
                    u16x4 hv;
                    #pragma unroll
                    for (int j = 0; j < 4; j++) hv[j] = f2bf(vv[j]);
                    *(u16x4*)&Bs[0][r*LDSS + kc] = hv;
                }
            }
        } else {
            // 4x4 in-register transpose: rows n0+4rb..+3, k kc..kc+3
            f32x4 c0 = *(const f32x4*)(Bp + (long)(k0 + kc + 0) * ldb + n0 + rb*4);
            f32x4 c1 = *(const f32x4*)(Bp + (long)(k0 + kc + 1) * ldb + n0 + rb*4);
            f32x4 c2 = *(const f32x4*)(Bp + (long)(k0 + kc + 2) * ldb + n0 + rb*4);
            f32x4 c3 = *(const f32x4*)(Bp + (long)(k0 + kc + 3) * ldb + n0 + rb*4);
            #pragma unroll
            for (int i = 0; i < 4; i++) {
                float x0 = c0[i], x1 = c1[i], x2 = c2[i], x3 = c3[i];
                int r = rb*4 + i;
                if (SPLIT == 3) {
                    u16x4 hv, mv, lv;
                    unsigned short h,m,l;
                    split3(x0,h,m,l); hv[0]=h; mv[0]=m; lv[0]=l;
                    split3(x1,h,m,l); hv[1]=h; mv[1]=m; lv[1]=l;
                    split3(x2,h,m,l); hv[2]=h; mv[2]=m; lv[2]=l;
                    split3(x3,h,m,l); hv[3]=h; mv[3]=m; lv[3]=l;
                    *(u16x4*)&Bs[0][r*LDSS + kc] = hv;
                    *(u16x4*)&Bs[1][r*LDSS + kc] = mv;
                    *(u16x4*)&Bs[2][r*LDSS + kc] = lv;
                } else {
                    u16x4 hv = {f2bf(x0), f2bf(x1), f2bf(x2), f2bf(x3)};
                    *(u16x4*)&Bs[0][r*LDSS + kc] = hv;
                }
            }
        }
        __syncthreads();

        bf16x8 af[SPLIT][4], bfv[SPLIT][4];
        #pragma unroll
        for (int s = 0; s < SPLIT; s++) {
            #pragma unroll
            for (int mi = 0; mi < 4; mi++)
                af[s][mi] = *(const bf16x8*)&As[s][(wm + mi*16 + lr)*LDSS + lg*8];
            #pragma unroll
            for (int ni = 0; ni < 4; ni++)
                bfv[s][ni] = *(const bf16x8*)&Bs[s][(wn + ni*16 + lr)*LDSS + lg*8];
        }
        #pragma unroll
        for (int mi = 0; mi < 4; mi++)
            #pragma unroll
            for (int ni = 0; ni < 4; ni++) {
                acc[mi][ni] = MFMA(af[0][mi], bfv[0][ni], acc[mi][ni]);
                if (SPLIT == 3) {
                    acc[mi][ni] = MFMA(af[0][mi], bfv[1][ni], acc[mi][ni]);
                    acc[mi][ni] = MFMA(af[1][mi], bfv[0][ni], acc[mi][ni]);
                    acc[mi][ni] = MFMA(af[0][mi], bfv[2][ni], acc[mi][ni]);
                    acc[mi][ni] = MFMA(af[1][mi], bfv[1][ni], acc[mi][ni]);
                    acc[mi][ni] = MFMA(af[2][mi], bfv[0][ni], acc[mi][ni]);
                }
            }
        __syncthreads();
    }

    #pragma unroll
    for (int mi = 0; mi < 4; mi++) {
        #pragma unroll
        for (int r = 0; r < 4; r++) {
            int rowl = wm + mi*16 + lg*4 + r;
            if (m0 + rowl < Mloc) {
                long crow = GROUPED ? (long)(off + m0 + rowl) : (long)(m0 + rowl);
                #pragma unroll
                for (int ni = 0; ni < 4; ni++) {
                    int col = n0 + wn + ni*16 + lr;
                    float val = acc[mi][ni][r];
                    if (EPI == 1) val += addsrc[crow * (long)ldc + col];
                    if (EPI == 2) {
                        float s = addsrc[crow * (long)ldc + col];
                        val *= s / (1.f + expf(-s));
                    }
                    C[cbase + crow * (long)ldc + col] = val;
                }
            }
        }
    }
}

// ---------------- fused MoE w1/w3 grouped GEMM: G = silu(A@w1)*(A@w3), f32 out ----------------
// B1/B3 staged sequentially into one Bs buffer (keeps LDS <= 61 KB at SPLIT=3).
template<int SPLIT>
__global__ __launch_bounds__(256) void moe13_kernel(
    const float* __restrict__ A, const float* __restrict__ W1,
    const float* __restrict__ W3, float* __restrict__ G,
    const int* __restrict__ rowidx, const int* __restrict__ counts,
    const int* __restrict__ offsets)
{
    __shared__ __align__(16) unsigned short As[SPLIT][128*LDSS];
    __shared__ __align__(16) unsigned short Bs[SPLIT][128*LDSS];

    int e = blockIdx.z;
    int cnt = counts[e], off = offsets[e];
    int n0 = blockIdx.x * 128;
    int m0 = blockIdx.y * 128;
    if (m0 >= cnt) return;
    const float* b1p = W1 + (long)e * (D_MODEL*FFH);
    const float* b3p = W3 + (long)e * (D_MODEL*FFH);

    int tid = threadIdx.x;
    int w = tid >> 6, lane = tid & 63;
    int wm = (w >> 1) << 6, wn = (w & 1) << 6;
    int lr = lane & 15, lg = lane >> 4;

    f32x4 zero = {0.f,0.f,0.f,0.f};
    f32x4 a1[4][4], a3[4][4];
    #pragma unroll
    for (int mi = 0; mi < 4; mi++)
        #pragma unroll
        for (int ni = 0; ni < 4; ni++) { a1[mi][ni] = zero; a3[mi][ni] = zero; }

    int rb = tid >> 3, kc = (tid & 7) << 2;

    for (int k0 = 0; k0 < D_MODEL; k0 += 32) {
        // stage A
        #pragma unroll
        for (int p = 0; p < 4; p++) {
            int r = p*32 + rb;
            f32x4 vv = zero;
            if (m0 + r < cnt) {
                long arow = (long)rowidx[off + m0 + r];
                vv = *(const f32x4*)(A + arow * (long)D_MODEL + k0 + kc);
            }
            if (SPLIT == 3) {
                u16x4 hv, mv, lv;
                #pragma unroll
                for (int j = 0; j < 4; j++) { unsigned short h,m,l; split3(vv[j],h,m,l); hv[j]=h; mv[j]=m; lv[j]=l; }
                *(u16x4*)&As[0][r*LDSS + kc] = hv;
                *(u16x4*)&As[1][r*LDSS + kc] = mv;
                *(u16x4*)&As[2][r*LDSS + kc] = lv;
            } else {
                u16x4 hv;
                #pragma unroll
                for (int j = 0; j < 4; j++) hv[j] = f2bf(vv[j]);
                *(u16x4*)&As[0][r*LDSS + kc] = hv;
            }
        }
        // two passes: W1 then W3
        #pragma unroll
        for (int pass = 0; pass < 2; pass++) {
            const float* bp = pass ? b3p : b1p;
            f32x4 c0 = *(const f32x4*)(bp + (long)(k0 + kc + 0) * FFH + n0 + rb*4);
            f32x4 c1 = *(const f32x4*)(bp + (long)(k0 + kc + 1) * FFH + n0 + rb*4);
            f32x4 c2 = *(const f32x4*)(bp + (long)(k0 + kc + 2) * FFH + n0 + rb*4);
            f32x4 c3 = *(const f32x4*)(bp + (long)(k0 + kc + 3) * FFH + n0 + rb*4);
            #pragma unroll
            for (int i = 0; i < 4; i++) {
                float x0 = c0[i], x1 = c1[i], x2 = c2[i], x3 = c3[i];
                int r = rb*4 + i;
                if (SPLIT == 3) {
                    u16x4 hv, mv, lv;
                    unsigned short h,m,l;
                    split3(x0,h,m,l); hv[0]=h; mv[0]=m; lv[0]=l;
                    split3(x1,h,m,l); hv[1]=h; mv[1]=m; lv[1]=l;
                    split3(x2,h,m,l); hv[2]=h; mv[2]=m; lv[2]=l;
                    split3(x3,h,m,l); hv[3]=h; mv[3]=m; lv[3]=l;
                    *(u16x4*)&Bs[0][r*LDSS + kc] = hv;
                    *(u16x4*)&Bs[1][r*LDSS + kc] = mv;
                    *(u16x4*)&Bs[2][r*LDSS + kc] = lv;
                } else {
                    u16x4 hv = {f2bf(x0), f2bf(x1), f2bf(x2), f2bf(x3)};
                    *(u16x4*)&Bs[0][r*LDSS + kc] = hv;
                }
            }
            __syncthreads();

            bf16x8 af[SPLIT][4], bfv[SPLIT][4];
            #pragma unroll
            for (int s = 0; s < SPLIT; s++) {
                #pragma unroll
                for (int mi = 0; mi < 4; mi++)
                    af[s][mi] = *(const bf16x8*)&As[s][(wm + mi*16 + lr)*LDSS + lg*8];
                #pragma unroll
                for (int ni = 0; ni < 4; ni++)
                    bfv[s][ni] = *(const bf16x8*)&Bs[s][(wn + ni*16 + lr)*LDSS + lg*8];
            }
            #pragma unroll
            for (int mi = 0; mi < 4; mi++)
                #pragma unroll
                for (int ni = 0; ni < 4; ni++) {
                    f32x4 a = pass ? a3[mi][ni] : a1[mi][ni];
                    a = MFMA(af[0][mi], bfv[0][ni], a);
                    if (SPLIT == 3) {
                        a = MFMA(af[0][mi], bfv[1][ni], a);
                        a = MFMA(af[1][mi], bfv[0][ni], a);
                        a = MFMA(af[0][mi], bfv[2][ni], a);
                        a = MFMA(af[1][mi], bfv[1][ni], a);
                        a = MFMA(af[2][mi], bfv[0][ni], a);
                    }
                    if (pass) a3[mi][ni] = a; else a1[mi][ni] = a;
                }
            __syncthreads();
        }
    }

    #pragma unroll
    for (int mi = 0; mi < 4; mi++) {
        #pragma unroll
        for (int r = 0; r < 4; r++) {
            int rowl = wm + mi*16 + lg*4 + r;
            if (m0 + rowl < cnt) {
                long crow = off + m0 + rowl;
                #pragma unroll
                for (int ni = 0; ni < 4; ni++) {
                    int col = n0 + wn + ni*16 + lr;
                    float v1 = a1[mi][ni][r];
                    float v3 = a3[mi][ni][r];
                    float sl = v1 / (1.f + expf(-v1));
                    G[crow * (long)FFH + col] = sl * v3;
                }
            }
        }
    }
}

// ---------------- flash attention (causal, split-bf16, 32-wide KV tiles) ----------------
__global__ __launch_bounds__(256) void attn_kernel(
    const float* __restrict__ q, const float* __restrict__ k,
    const float* __restrict__ v, float* __restrict__ att)
{
    __shared__ __align__(16) unsigned short Qs[3][64*72];
    __shared__ __align__(16) unsigned short KP[3][2560];
    __shared__ __align__(16) unsigned short Vt[3][2560];

    int qt = blockIdx.x, bh = blockIdx.y;
    int b = bh >> 4, hh = bh & 15;
    int tid = threadIdx.x, w = tid >> 6, lane = tid & 63;
    int lr = lane & 15, lg = lane >> 4;
    int lrow = tid >> 4;
    int lcol = (tid & 15) << 2;

    const float* qbase = q + ((long)(b*SEQ + qt*64) * D_MODEL + hh*64);
    #pragma unroll
    for (int p = 0; p < 4; p++) {
        int r = p*16 + lrow;
        f32x4 vv = *(const f32x4*)(qbase + (long)r * D_MODEL + lcol);
        #pragma unroll
        for (int jj = 0; jj < 4; jj++) {
            unsigned short h,m,l; split3(vv[jj],h,m,l);
            Qs[0][r*72 + lcol + jj] = h;
            Qs[1][r*72 + lcol + jj] = m;
            Qs[2][r*72 + lcol + jj] = l;
        }
    }

    f32x4 zero = {0.f,0.f,0.f,0.f};
    f32x4 oacc[4] = {zero, zero, zero, zero};
    float mrun[4] = {-INFINITY,-INFINITY,-INFINITY,-INFINITY};
    float lrun[4] = {0.f,0.f,0.f,0.f};

    int ntile = 2*qt + 2;
    for (int jt = 0; jt < ntile; jt++) {
        const float* kbase = k + ((long)(b*SEQ + jt*32) * D_MODEL + hh*64);
        const float* vbase = v + ((long)(b*SEQ + jt*32) * D_MODEL + hh*64);
        #pragma unroll
        for (int p = 0; p < 2; p++) {
            int r = p*16 + lrow;
            f32x4 kv4 = *(const f32x4*)(kbase + (long)r * D_MODEL + lcol);
            f32x4 vv4 = *(const f32x4*)(vbase + (long)r * D_MODEL + lcol);
            #pragma unroll
            for (int jj = 0; jj < 4; jj++) {
                unsigned short h,m,l;
                split3(kv4[jj],h,m,l);
                KP[0][r*72 + lcol + jj] = h;
                KP[1][r*72 + lcol + jj] = m;
                KP[2][r*72 + lcol + jj] = l;
                split3(vv4[jj],h,m,l);
                Vt[0][(lcol+jj)*40 + r] = h;
                Vt[1][(lcol+jj)*40 + r] = m;
                Vt[2][(lcol+jj)*40 + r] = l;
            }
        }
        __syncthreads();

        f32x4 s[2] = {zero, zero};
        #pragma unroll
        for (int ks = 0; ks < 2; ks++) {
            bf16x8 qh = *(const bf16x8*)&Qs[0][(w*16 + lr)*72 + ks*32 + lg*8];
            bf16x8 qm = *(const bf16x8*)&Qs[1][(w*16 + lr)*72 + ks*32 + lg*8];
            bf16x8 ql = *(const bf16x8*)&Qs[2][(w*16 + lr)*72 + ks*32 + lg*8];
            #pragma unroll
            for (int ni = 0; ni < 2; ni++) {
                bf16x8 kh = *(const bf16x8*)&KP[0][(ni*16 + lr)*72 + ks*32 + lg*8];
                bf16x8 km = *(const bf16x8*)&KP[1][(ni*16 + lr)*72 + ks*32 + lg*8];
                bf16x8 kl = *(const bf16x8*)&KP[2][(ni*16 + lr)*72 + ks*32 + lg*8];
                s[ni] = MFMA(qh, kh, s[ni]);
                s[ni] = MFMA(qh, km, s[ni]);
                s[ni] = MFMA(qm, kh, s[ni]);
                s[ni] = MFMA(qh, kl, s[ni]);
                s[ni] = MFMA(qm, km, s[ni]);
                s[ni] = MFMA(ql, kh, s[ni]);
            }
        }
        __syncthreads();

        #pragma unroll
        for (int r = 0; r < 4; r++) {
            int qg = qt*64 + w*16 + lg*4 + r;
            float mx = -INFINITY;
            #pragma unroll
            for (int ni = 0; ni < 2; ni++) {
                int kg = jt*32 + ni*16 + lr;
                float val = s[ni][r] * 0.125f;
                if (kg > qg) val = -INFINITY;
                s[ni][r] = val;
                mx = fmaxf(mx, val);
            }
            #pragma unroll
            for (int dd = 1; dd < 16; dd <<= 1)
                mx = fmaxf(mx, __shfl_xor(mx, dd));
            float mnew  = fmaxf(mrun[r], mx);
            float alpha = expf(mrun[r] - mnew);
            float ps = 0.f;
            #pragma unroll
            for (int ni = 0; ni < 2; ni++) {
                float pv = expf(s[ni][r] - mnew);
                s[ni][r] = pv;
                ps += pv;
            }
            #pragma unroll
            for (int dd = 1; dd < 16; dd <<= 1)
                ps += __shfl_xor(ps, dd);
            lrun[r] = lrun[r] * alpha + ps;
            mrun[r] = mnew;
            #pragma unroll
            for (int d = 0; d < 4; d++) oacc[d][r] *= alpha;
            int prow = w*16 + lg*4 + r;
            #pragma unroll
            for (int ni = 0; ni < 2; ni++) {
                unsigned short h,m,l; split3(s[ni][r],h,m,l);
                KP[0][prow*40 + ni*16 + lr] = h;
                KP[1][prow*40 + ni*16 + lr] = m;
                KP[2][prow*40 + ni*16 + lr] = l;
            }
        }

        {
            bf16x8 ph = *(const bf16x8*)&KP[0][(w*16 + lr)*40 + lg*8];
            bf16x8 pm = *(const bf16x8*)&KP[1][(w*16 + lr)*40 + lg*8];
            bf16x8 pl = *(const bf16x8*)&KP[2][(w*16 + lr)*40 + lg*8];
            #pragma unroll
            for (int ni = 0; ni < 4; ni++) {
                bf16x8 vh = *(const bf16x8*)&Vt[0][(ni*16 + lr)*40 + lg*8];
                bf16x8 vm = *(const bf16x8*)&Vt[1][(ni*16 + lr)*40 + lg*8];
                bf16x8 vl = *(const bf16x8*)&Vt[2][(ni*16 + lr)*40 + lg*8];
                oacc[ni] = MFMA(ph, vh, oacc[ni]);
                oacc[ni] = MFMA(ph, vm, oacc[ni]);
                oacc[ni] = MFMA(pm, vh, oacc[ni]);
                oacc[ni] = MFMA(ph, vl, oacc[ni]);
                oacc[ni] = MFMA(pm, vm, oacc[ni]);
                oacc[ni] = MFMA(pl, vh, oacc[ni]);
            }
        }
        __syncthreads();
    }

    float* obase = att + ((long)(b*SEQ + qt*64) * D_MODEL + hh*64);
    #pragma unroll
    for (int r = 0; r < 4; r++) {
        float inv = 1.f / lrun[r];
        #pragma unroll
        for (int ni = 0; ni < 4; ni++)
            obase[(long)(w*16 + lg*4 + r) * D_MODEL + ni*16 + lr] = oacc[ni][r] * inv;
    }
}

// ---------------- small kernels ----------------
__global__ __launch_bounds__(256) void embed_kernel(const int* __restrict__ tok,
    const float* __restrict__ emb, float* __restrict__ h)
{
    int n = blockIdx.x;
    int c = threadIdx.x << 2;
    long t = tok[n];
    *(f32x4*)(h + (long)n*D_MODEL + c) = *(const f32x4*)(emb + t*D_MODEL + c);
}

__global__ __launch_bounds__(256) void rmsnorm_kernel(const float* __restrict__ x,
    const float* __restrict__ wt, float* __restrict__ out)
{
    __shared__ float red[4];
    int n = blockIdx.x;
    int c = threadIdx.x << 2;
    f32x4 v = *(const f32x4*)(x + (long)n*D_MODEL + c);
    float ss = v.x*v.x + v.y*v.y + v.z*v.z + v.w*v.w;
    #pragma unroll
    for (int dd = 32; dd; dd >>= 1) ss += __shfl_xor(ss, dd);
    if ((threadIdx.x & 63) == 0) red[threadIdx.x >> 6] = ss;
    __syncthreads();
    float tot = red[0] + red[1] + red[2] + red[3];
    float rms = rsqrtf(tot * (1.f / D_MODEL) + 1e-6f);
    f32x4 wv = *(const f32x4*)(wt + c);
    f32x4 o = v * rms;
    o = o * wv;
    *(f32x4*)(out + (long)n*D_MODEL + c) = o;
}

__global__ __launch_bounds__(256) void ropetab_kernel(float* __restrict__ tab)
{
    int idx = blockIdx.x * 256 + threadIdx.x;   // 32768 = 1024 t x 32 i
    if (idx >= SEQ * 32) return;
    int t = idx >> 5, i = idx & 31;
    double inv = pow(10000.0, -(double)(2*i) / 64.0);
    double ang = (double)t * inv;
    tab[idx*2]   = (float)cos(ang);
    tab[idx*2+1] = (float)sin(ang);
}

__global__ __launch_bounds__(256) void rope_kernel(float* __restrict__ q, float* __restrict__ kk,
    const float* __restrict__ tab)
{
    int gid = blockIdx.x * 256 + threadIdx.x;
    if (gid >= NTOK * 512) return;
    int n   = gid >> 9;
    int rem = gid & 511;
    int hh  = rem >> 5;
    int i   = rem & 31;
    int t   = n & (SEQ - 1);
    float cs = tab[(t*32 + i)*2];
    float sn = tab[(t*32 + i)*2 + 1];
    long base = (long)n * D_MODEL + hh*64 + 2*i;
    float qr = q[base], qi = q[base+1];
    q[base]   = qr*cs - qi*sn;
    q[base+1] = qr*sn + qi*cs;
    float kr = kk[base], ki = kk[base+1];
    kk[base]   = kr*cs - ki*sn;
    kk[base+1] = kr*sn + ki*cs;
}

__global__ __launch_bounds__(64) void gate_kernel(const float* __restrict__ xf,
    const float* __restrict__ gw, int* __restrict__ counts,
    int* __restrict__ eid, float* __restrict__ wts, float* __restrict__ pbuf)
{
    int n = blockIdx.x;
    int lane = threadIdx.x;
    float acc[8] = {0,0,0,0,0,0,0,0};
    const float* xr = xf + (long)n * D_MODEL;
    for (int d = lane; d < D_MODEL; d += 64) {
        float xv = xr[d];
        const float* g = gw + d * 8;
        #pragma unroll
        for (int e = 0; e < 8; e++) acc[e] += xv * g[e];
    }
    #pragma unroll
    for (int e = 0; e < 8; e++) {
        #pragma unroll
        for (int dd = 32; dd; dd >>= 1) acc[e] += __shfl_xor(acc[e], dd);
    }
    if (lane == 0) {
        float mx = acc[0];
        #pragma unroll
        for (int e = 1; e < 8; e++) mx = fmaxf(mx, acc[e]);
        float pe[8], ssum = 0.f;
        #pragma unroll
        for (int e = 0; e < 8; e++) { pe[e] = expf(acc[e] - mx); ssum += pe[e]; }
        float sinv = 1.f / ssum;
        #pragma unroll
        for (int e = 0; e < 8; e++) { pe[e] *= sinv; pbuf[n*8 + e] = pe[e]; }
        int e1 = 0;
        #pragma unroll
        for (int e = 1; e < 8; e++) if (pe[e] > pe[e1]) e1 = e;
        int e2 = -1;
        #pragma unroll
        for (int e = 0; e < 8; e++) if (e != e1 && (e2 < 0 || pe[e] > pe[e2])) e2 = e;
        float v1 = pe[e1], v2 = pe[e2];
        float wsum = v1 + v2 + 1e-8f;
        eid[n*2] = e1; eid[n*2+1] = e2;
        wts[n*2] = v1 / wsum; wts[n*2+1] = v2 / wsum;
        atomicAdd(counts + e1, 1);
        atomicAdd(counts + e2, 1);
    }
}

__global__ __launch_bounds__(64) void scan_kernel(const int* __restrict__ counts,
    int* __restrict__ offs, int* __restrict__ cursor,
    const float* __restrict__ pbuf, float* __restrict__ aux)
{
    int t = threadIdx.x;
    int e = t & 7, c = t >> 3;          // 8 experts x 8 chunks
    float s = 0.f;
    for (int n = 0; n < NTOK/8; n++)
        s += pbuf[(c*(NTOK/8) + n)*8 + e];
    #pragma unroll
    for (int dd = 8; dd < 64; dd <<= 1) s += __shfl_xor(s, dd);
    __shared__ float red[8];
    if (t < 8) red[t] = s;
    __syncthreads();
    if (t == 0) {
        int o = 0; float a = 0.f;
        for (int k = 0; k < 8; k++) {
            offs[k] = o; cursor[k] = o; o += counts[k];
            a += (float)counts[k] * red[k];
        }
        aux[0] += 8.f * a / ((float)NTOK * (float)NTOK);
    }
}

__global__ __launch_bounds__(256) void assign_kernel(const int* __restrict__ eid,
    int* __restrict__ cursor, int* __restrict__ rowidx, int* __restrict__ tpos)
{
    int n = blockIdx.x * 256 + threadIdx.x;
    if (n >= NTOK) return;
    #pragma unroll
    for (int s = 0; s < 2; s++) {
        int e = eid[n*2 + s];
        int p = atomicAdd(cursor + e, 1);
        rowidx[p] = n;
        tpos[n*2 + s] = p;
    }
}

__global__ __launch_bounds__(256) void combine_kernel(
    float* __restrict__ h, const float* __restrict__ eob,
    const int* __restrict__ tpos, const float* __restrict__ wts)
{
    int n = blockIdx.x;
    int c = threadIdx.x << 2;
    int p0 = tpos[n*2], p1 = tpos[n*2+1];
    float w0 = wts[n*2], w1 = wts[n*2+1];
    f32x4 hv = *(const f32x4*)(h   + (long)n  * D_MODEL + c);
    f32x4 e0 = *(const f32x4*)(eob + (long)p0 * D_MODEL + c);
    f32x4 e1 = *(const f32x4*)(eob + (long)p1 * D_MODEL + c);
    hv = hv + w0 * e0 + w1 * e1;
    *(f32x4*)(h + (long)n * D_MODEL + c) = hv;
}

__global__ void write_aux_kernel(float* __restrict__ out, const float* __restrict__ aux)
{
    if (threadIdx.x == 0 && blockIdx.x == 0)
        out[(long)NTOK * VOCAB] = aux[0];
}

// ---------------- launch ----------------
extern "C" void kernel_launch(void* const* d_in, const int* in_sizes, int n_in,
                              void* d_out, int out_size, void* d_ws, size_t ws_size,
                              hipStream_t stream)
{
    const int*   tokens = (const int*)d_in[0];
    const float* emb    = (const float*)d_in[1];
    const float* anw    = (const float*)d_in[2];
    const float* wq     = (const float*)d_in[3];
    const float* wk     = (const float*)d_in[4];
    const float* wv     = (const float*)d_in[5];
    const float* wo     = (const float*)d_in[6];
    const float* fnw    = (const float*)d_in[7];
    const float* gw     = (const float*)d_in[8];
    const float* w1     = (const float*)d_in[9];
    const float* w2     = (const float*)d_in[10];
    const float* w3     = (const float*)d_in[11];
    const float* finw   = (const float*)d_in[12];
    float* out = (float*)d_out;

    char* W = (char*)d_ws;
    const size_t MB = 1024u * 1024u;
    int*   counts = (int*)(W + 0);
    int*   offs   = (int*)(W + 32);
    int*   cursor = (int*)(W + 64);
    float* aux    = (float*)(W + 96);
    int*   eid    = (int*)(W + 1024);
    int*   tpos   = (int*)(W + 1024 + 16384);
    float* wts    = (float*)(W + 1024 + 32768);
    int*   rowix  = (int*)(W + 1024 + 49152);
    float* pbuf   = (float*)(W + 1024 + 65536);
    float* rtab   = (float*)(W + 256*1024);
    float* h    = (float*)(W + 1*MB);
    float* hn   = (float*)(W + 9*MB);
    float* qkv  = (float*)(W + 17*MB);                // [3][NTOK][D]: 24 MB -> 41
    float* att  = (float*)(W + 41*MB);                // 8 MB -> 49
    float* g    = (float*)(W + 17*MB);                // MoE phase: 32 MB (qkv/att dead)
    float* eob  = (float*)(W + 49*MB);                // 16 MB -> 65
    float* qb = qkv, *kb = qkv + (long)NTOK*D_MODEL, *vb = qkv + 2l*NTOK*D_MODEL;

    hipMemsetAsync(W, 0, 100, stream);
    ropetab_kernel<<<(SEQ*32 + 255)/256, 256, 0, stream>>>(rtab);
    embed_kernel<<<NTOK, 256, 0, stream>>>(tokens, emb, h);

    for (int l = 0; l < 2; l++) {
        rmsnorm_kernel<<<NTOK, 256, 0, stream>>>(h, anw + (size_t)l*D_MODEL, hn);

        const float* wql = wq + (size_t)l*D_MODEL*D_MODEL;
        const float* wkl = wk + (size_t)l*D_MODEL*D_MODEL;
        const float* wvl = wv + (size_t)l*D_MODEL*D_MODEL;
        const float* wol = wo + (size_t)l*D_MODEL*D_MODEL;

        // fused QKV: one dispatch, z selects weight
        gemm_kernel<3,0,0,0,0,0,1><<<dim3(D_MODEL/128, NTOK/128, 3), 256, 0, stream>>>(
            hn, wql, wkl, wvl, qkv, nullptr, nullptr, nullptr, nullptr,
            NTOK, D_MODEL, D_MODEL, D_MODEL, D_MODEL, D_MODEL, 0);

        rope_kernel<<<(NTOK*512 + 255)/256, 256, 0, stream>>>(qb, kb, rtab);

        attn_kernel<<<dim3(SEQ/64, BATCH*NHEADS), 256, 0, stream>>>(qb, kb, vb, att);

        gemm_kernel<3,0,1,0,0,0,0><<<dim3(D_MODEL/128, NTOK/128), 256, 0, stream>>>(
            att, wol, nullptr, nullptr, h, h, nullptr, nullptr, nullptr,
            NTOK, D_MODEL, D_MODEL, D_MODEL, D_MODEL, D_MODEL, 0);

        rmsnorm_kernel<<<NTOK, 256, 0, stream>>>(h, fnw + (size_t)l*D_MODEL, hn);

        hipMemsetAsync(W, 0, 96, stream);
        gate_kernel<<<NTOK, 64, 0, stream>>>(hn, gw + (size_t)l*D_MODEL*NEXP, counts, eid, wts, pbuf);
        scan_kernel<<<1, 64, 0, stream>>>(counts, offs, cursor, pbuf, aux);
        assign_kernel<<<(NTOK + 255)/256, 256, 0, stream>>>(eid, cursor, rowix, tpos);

        const float* w1l = w1 + (size_t)l*NEXP*D_MODEL*FFH;
        const float* w3l = w3 + (size_t)l*NEXP*D_MODEL*FFH;
        const float* w2l = w2 + (size_t)l*NEXP*FFH*D_MODEL;

        dim3 g13(FFH/128, 2*NTOK/128, NEXP);
        dim3 g2(D_MODEL/128, 2*NTOK/128, NEXP);
        if (l == 0) {
            // layer-1 MoE feeds layer-2 gate: keep f32-accurate
            moe13_kernel<3><<<g13, 256, 0, stream>>>(hn, w1l, w3l, g, rowix, counts, offs);
            gemm_kernel<3,0,0,1,0,0,0><<<g2, 256, 0, stream>>>(g, w2l, nullptr, nullptr, eob, nullptr,
                rowix, counts, offs, NTOK, D_MODEL, FFH, FFH, D_MODEL, D_MODEL, (long)FFH*D_MODEL);
        } else {
            // layer-2 MoE is downstream of all gates: plain bf16 is plenty
            moe13_kernel<1><<<g13, 256, 0, stream>>>(hn, w1l, w3l, g, rowix, counts, offs);
            gemm_kernel<1,0,0,1,0,0,0><<<g2, 256, 0, stream>>>(g, w2l, nullptr, nullptr, eob, nullptr,
                rowix, counts, offs, NTOK, D_MODEL, FFH, FFH, D_MODEL, D_MODEL, (long)FFH*D_MODEL);
        }

        combine_kernel<<<NTOK, 256, 0, stream>>>(h, eob, tpos, wts);
    }

    rmsnorm_kernel<<<NTOK, 256, 0, stream>>>(h, finw, hn);
    gemm_kernel<1,1,0,0,0,1,0><<<dim3(NTOK/128, VOCAB/128), 256, 0, stream>>>(
        hn, emb, nullptr, nullptr, out, nullptr, nullptr, nullptr, nullptr,
        NTOK, VOCAB, D_MODEL, D_MODEL, D_MODEL, VOCAB, 0);
    write_aux_kernel<<<1, 1, 0, stream>>>(out, aux);
}

// Round 6
// 2388.771 us; speedup vs baseline: 3.1173x; 1.1198x over previous
//
#include <hip/hip_runtime.h>
#include <hip/hip_bf16.h>
#include <math.h>

#define D_MODEL 1024
#define NHEADS  16
#define HDIM    64
#define NEXP    8
#define FFH     2048
#define BATCH   2
#define SEQ     1024
#define NTOK    2048
#define VOCAB   32000
#define LDSS    40   // LDS row stride in shorts (80 B): conflict-light ds_read_b128

typedef __attribute__((ext_vector_type(4))) float f32x4;
typedef __attribute__((ext_vector_type(2))) float f32x2;
typedef __attribute__((ext_vector_type(8))) __bf16 bf16x8;
typedef __attribute__((ext_vector_type(4))) unsigned short u16x4;

__device__ __forceinline__ unsigned short f2bf(float f) {
    union { float f; unsigned u; } v; v.f = f;
    unsigned r = v.u + 0x7FFFu + ((v.u >> 16) & 1u);
    return (unsigned short)(r >> 16);
}
__device__ __forceinline__ float bf2f(unsigned short u) {
    union { unsigned u; float f; } v; v.u = ((unsigned)u) << 16; return v.f;
}
__device__ __forceinline__ void split3(float x, unsigned short& h, unsigned short& m, unsigned short& l) {
    h = f2bf(x);
    float r1 = x - bf2f(h);
    m = f2bf(r1);
    float r2 = r1 - bf2f(m);
    l = f2bf(r2);
}

#define MFMA(a, b, c) __builtin_amdgcn_mfma_f32_16x16x32_bf16((a), (b), (c), 0, 0, 0)

#define PSA ((long)NTOK * D_MODEL)       // activation plane stride
#define PSW ((long)D_MODEL * D_MODEL)    // weight plane stride

// ---------------- rmsnorm -> 3 bf16 planes ----------------
__global__ __launch_bounds__(256) void rmsnorm_kernel(const float* __restrict__ x,
    const float* __restrict__ wt, unsigned short* __restrict__ out3)
{
    __shared__ float red[4];
    int n = blockIdx.x;
    int c = threadIdx.x << 2;
    f32x4 v = *(const f32x4*)(x + (long)n*D_MODEL + c);
    float ss = v.x*v.x + v.y*v.y + v.z*v.z + v.w*v.w;
    #pragma unroll
    for (int dd = 32; dd; dd >>= 1) ss += __shfl_xor(ss, dd);
    if ((threadIdx.x & 63) == 0) red[threadIdx.x >> 6] = ss;
    __syncthreads();
    float tot = red[0] + red[1] + red[2] + red[3];
    float rms = rsqrtf(tot * (1.f / D_MODEL) + 1e-6f);
    f32x4 wv = *(const f32x4*)(wt + c);
    f32x4 o = v * rms;
    o = o * wv;
    u16x4 hv, mv, lv;
    #pragma unroll
    for (int j = 0; j < 4; j++) { unsigned short h,m,l; split3(o[j],h,m,l); hv[j]=h; mv[j]=m; lv[j]=l; }
    long idx = (long)n*D_MODEL + c;
    *(u16x4*)(out3 + 0*PSA + idx) = hv;
    *(u16x4*)(out3 + 1*PSA + idx) = mv;
    *(u16x4*)(out3 + 2*PSA + idx) = lv;
}

// ---------------- weight transpose+split: W[K][N] f32 -> out[p][N][K] bf16 ----------------
__global__ __launch_bounds__(256) void wsplitT_kernel(
    const float* __restrict__ src, unsigned short* __restrict__ dst)
{
    __shared__ float t[64][65];
    int k0 = blockIdx.x*64, n0 = blockIdx.y*64;
    int tid = threadIdx.x;
    int a = tid & 63, g = tid >> 6;
    #pragma unroll 4
    for (int i = 0; i < 16; i++) {
        int k = g*16 + i;
        t[k][a] = src[(long)(k0+k)*D_MODEL + n0 + a];
    }
    __syncthreads();
    #pragma unroll 4
    for (int i = 0; i < 16; i++) {
        int n = g*16 + i;
        float v = t[a][n];               // k = a
        unsigned short h,m,l; split3(v,h,m,l);
        long idx = (long)(n0+n)*D_MODEL + k0 + a;
        dst[0*PSW + idx] = h;
        dst[1*PSW + idx] = m;
        dst[2*PSW + idx] = l;
    }
}

// ---------------- QKV (one projection): A planes x B planes -> out planes (64x128 tile) ----------------
__global__ __launch_bounds__(256, 3) void qkv_kernel(
    const unsigned short* __restrict__ A3,
    const unsigned short* __restrict__ B3, unsigned short* __restrict__ out)
{
    __shared__ __align__(16) unsigned short As[3][64*LDSS];
    __shared__ __align__(16) unsigned short Bs[3][128*LDSS];
    int n0 = blockIdx.x*128, m0 = blockIdx.y*64;
    int tid = threadIdx.x, w = tid >> 6, lane = tid & 63;
    int wm = (w >> 1)*32, wn = (w & 1)*64;
    int lr = lane & 15, lg = lane >> 4;
    f32x4 zero = {0.f,0.f,0.f,0.f};
    f32x4 acc[2][4];
    #pragma unroll
    for (int mi = 0; mi < 2; mi++)
        #pragma unroll
        for (int ni = 0; ni < 4; ni++) acc[mi][ni] = zero;
    int rb = tid >> 3, kc = (tid & 7) << 2;

    for (int k0 = 0; k0 < D_MODEL; k0 += 32) {
        #pragma unroll
        for (int p = 0; p < 2; p++) {
            int r = p*32 + rb;
            #pragma unroll
            for (int s = 0; s < 3; s++)
                *(u16x4*)&As[s][r*LDSS + kc] = *(const u16x4*)(A3 + s*PSA + (long)(m0+r)*D_MODEL + k0 + kc);
        }
        #pragma unroll
        for (int p = 0; p < 4; p++) {
            int r = p*32 + rb;
            #pragma unroll
            for (int s = 0; s < 3; s++)
                *(u16x4*)&Bs[s][r*LDSS + kc] = *(const u16x4*)(B3 + s*PSW + (long)(n0+r)*D_MODEL + k0 + kc);
        }
        __syncthreads();
        bf16x8 bf[3][4];
        #pragma unroll
        for (int s = 0; s < 3; s++)
            #pragma unroll
            for (int ni = 0; ni < 4; ni++)
                bf[s][ni] = *(const bf16x8*)&Bs[s][(wn + ni*16 + lr)*LDSS + lg*8];
        #pragma unroll
        for (int mi = 0; mi < 2; mi++) {
            bf16x8 ah = *(const bf16x8*)&As[0][(wm + mi*16 + lr)*LDSS + lg*8];
            bf16x8 am = *(const bf16x8*)&As[1][(wm + mi*16 + lr)*LDSS + lg*8];
            bf16x8 al = *(const bf16x8*)&As[2][(wm + mi*16 + lr)*LDSS + lg*8];
            #pragma unroll
            for (int ni = 0; ni < 4; ni++) {
                acc[mi][ni] = MFMA(ah, bf[0][ni], acc[mi][ni]);
                acc[mi][ni] = MFMA(ah, bf[1][ni], acc[mi][ni]);
                acc[mi][ni] = MFMA(am, bf[0][ni], acc[mi][ni]);
                acc[mi][ni] = MFMA(ah, bf[2][ni], acc[mi][ni]);
                acc[mi][ni] = MFMA(am, bf[1][ni], acc[mi][ni]);
                acc[mi][ni] = MFMA(al, bf[0][ni], acc[mi][ni]);
            }
        }
        __syncthreads();
    }
    #pragma unroll
    for (int mi = 0; mi < 2; mi++)
        #pragma unroll
        for (int r = 0; r < 4; r++) {
            long row = m0 + wm + mi*16 + lg*4 + r;
            #pragma unroll
            for (int ni = 0; ni < 4; ni++) {
                int col = n0 + wn + ni*16 + lr;
                unsigned short h,m,l; split3(acc[mi][ni][r], h,m,l);
                out[0*PSA + row*D_MODEL + col] = h;
                out[1*PSA + row*D_MODEL + col] = m;
                out[2*PSA + row*D_MODEL + col] = l;
            }
        }
}

// ---------------- WO: A f32 x B f32 (both split in-kernel), h += (64x64 tile) ----------------
__global__ __launch_bounds__(256, 2) void wo_kernel(
    const float* __restrict__ A, const float* __restrict__ B, float* h)
{
    __shared__ __align__(16) unsigned short As[3][64*LDSS];
    __shared__ __align__(16) unsigned short Bs[3][64*LDSS];
    int n0 = blockIdx.x*64, m0 = blockIdx.y*64;
    int tid = threadIdx.x, w = tid >> 6, lane = tid & 63;
    int wm = (w >> 1)*32, wn = (w & 1)*32;
    int lr = lane & 15, lg = lane >> 4;
    f32x4 zero = {0.f,0.f,0.f,0.f};
    f32x4 acc[2][2];
    #pragma unroll
    for (int mi = 0; mi < 2; mi++)
        #pragma unroll
        for (int ni = 0; ni < 2; ni++) acc[mi][ni] = zero;
    int rb = tid >> 3, kc = (tid & 7) << 2;      // A staging
    int nb = (tid & 31) << 1, kb = (tid >> 5) << 2;  // B staging

    for (int k0 = 0; k0 < D_MODEL; k0 += 32) {
        #pragma unroll
        for (int p = 0; p < 2; p++) {
            int r = p*32 + rb;
            f32x4 vv = *(const f32x4*)(A + (long)(m0+r)*D_MODEL + k0 + kc);
            u16x4 hv, mv, lv;
            #pragma unroll
            for (int j = 0; j < 4; j++) { unsigned short h,m,l; split3(vv[j],h,m,l); hv[j]=h; mv[j]=m; lv[j]=l; }
            *(u16x4*)&As[0][r*LDSS + kc] = hv;
            *(u16x4*)&As[1][r*LDSS + kc] = mv;
            *(u16x4*)&As[2][r*LDSS + kc] = lv;
        }
        {
            f32x2 c0 = *(const f32x2*)(B + (long)(k0+kb+0)*D_MODEL + n0 + nb);
            f32x2 c1 = *(const f32x2*)(B + (long)(k0+kb+1)*D_MODEL + n0 + nb);
            f32x2 c2 = *(const f32x2*)(B + (long)(k0+kb+2)*D_MODEL + n0 + nb);
            f32x2 c3 = *(const f32x2*)(B + (long)(k0+kb+3)*D_MODEL + n0 + nb);
            #pragma unroll
            for (int i = 0; i < 2; i++) {
                int r = nb + i;
                u16x4 hv, mv, lv;
                unsigned short h,m,l;
                split3(c0[i],h,m,l); hv[0]=h; mv[0]=m; lv[0]=l;
                split3(c1[i],h,m,l); hv[1]=h; mv[1]=m; lv[1]=l;
                split3(c2[i],h,m,l); hv[2]=h; mv[2]=m; lv[2]=l;
                split3(c3[i],h,m,l); hv[3]=h; mv[3]=m; lv[3]=l;
                *(u16x4*)&Bs[0][r*LDSS + kb] = hv;
                *(u16x4*)&Bs[1][r*LDSS + kb] = mv;
                *(u16x4*)&Bs[2][r*LDSS + kb] = lv;
            }
        }
        __syncthreads();
        bf16x8 bf[3][2];
        #pragma unroll
        for (int s = 0; s < 3; s++)
            #pragma unroll
            for (int ni = 0; ni < 2; ni++)
                bf[s][ni] = *(const bf16x8*)&Bs[s][(wn + ni*16 + lr)*LDSS + lg*8];
        #pragma unroll
        for (int mi = 0; mi < 2; mi++) {
            bf16x8 ah = *(const bf16x8*)&As[0][(wm + mi*16 + lr)*LDSS + lg*8];
            bf16x8 am = *(const bf16x8*)&As[1][(wm + mi*16 + lr)*LDSS + lg*8];
            bf16x8 al = *(const bf16x8*)&As[2][(wm + mi*16 + lr)*LDSS + lg*8];
            #pragma unroll
            for (int ni = 0; ni < 2; ni++) {
                acc[mi][ni] = MFMA(ah, bf[0][ni], acc[mi][ni]);
                acc[mi][ni] = MFMA(ah, bf[1][ni], acc[mi][ni]);
                acc[mi][ni] = MFMA(am, bf[0][ni], acc[mi][ni]);
                acc[mi][ni] = MFMA(ah, bf[2][ni], acc[mi][ni]);
                acc[mi][ni] = MFMA(am, bf[1][ni], acc[mi][ni]);
                acc[mi][ni] = MFMA(al, bf[0][ni], acc[mi][ni]);
            }
        }
        __syncthreads();
    }
    #pragma unroll
    for (int mi = 0; mi < 2; mi++)
        #pragma unroll
        for (int r = 0; r < 4; r++) {
            long row = m0 + wm + mi*16 + lg*4 + r;
            #pragma unroll
            for (int ni = 0; ni < 2; ni++) {
                int col = n0 + wn + ni*16 + lr;
                h[row*D_MODEL + col] += acc[mi][ni][r];
            }
        }
}

// ---------------- fused MoE w1/w3: A planes gathered x B f32 dual -> g f32 (128x128) ----------------
template<int SPLIT>
__global__ __launch_bounds__(256, 2) void moe13_kernel(
    const unsigned short* __restrict__ A3, const float* __restrict__ W1,
    const float* __restrict__ W3, float* __restrict__ G,
    const int* __restrict__ rowidx, const int* __restrict__ counts,
    const int* __restrict__ offsets)
{
    __shared__ __align__(16) unsigned short As[SPLIT][128*LDSS];
    __shared__ __align__(16) unsigned short Bs[SPLIT][128*LDSS];
    int e = blockIdx.z;
    int cnt = counts[e], off = offsets[e];
    int n0 = blockIdx.x*128, m0 = blockIdx.y*128;
    if (m0 >= cnt) return;
    const float* b1p = W1 + (long)e * (D_MODEL*FFH);
    const float* b3p = W3 + (long)e * (D_MODEL*FFH);
    int tid = threadIdx.x, w = tid >> 6, lane = tid & 63;
    int wm = (w >> 1)*64, wn = (w & 1)*64;
    int lr = lane & 15, lg = lane >> 4;
    f32x4 zero = {0.f,0.f,0.f,0.f};
    f32x4 a1[4][4], a3[4][4];
    #pragma unroll
    for (int mi = 0; mi < 4; mi++)
        #pragma unroll
        for (int ni = 0; ni < 4; ni++) { a1[mi][ni] = zero; a3[mi][ni] = zero; }
    int rb = tid >> 3, kc = (tid & 7) << 2;

    for (int k0 = 0; k0 < D_MODEL; k0 += 32) {
        #pragma unroll
        for (int p = 0; p < 4; p++) {
            int r = p*32 + rb;
            u16x4 z4 = {0,0,0,0};
            if (m0 + r < cnt) {
                long arow = (long)rowidx[off + m0 + r];
                #pragma unroll
                for (int s = 0; s < SPLIT; s++)
                    *(u16x4*)&As[s][r*LDSS + kc] = *(const u16x4*)(A3 + s*PSA + arow*D_MODEL + k0 + kc);
            } else {
                #pragma unroll
                for (int s = 0; s < SPLIT; s++)
                    *(u16x4*)&As[s][r*LDSS + kc] = z4;
            }
        }
        #pragma unroll
        for (int pass = 0; pass < 2; pass++) {
            const float* bp = pass ? b3p : b1p;
            f32x4 c0 = *(const f32x4*)(bp + (long)(k0+kc+0)*FFH + n0 + rb*4);
            f32x4 c1 = *(const f32x4*)(bp + (long)(k0+kc+1)*FFH + n0 + rb*4);
            f32x4 c2 = *(const f32x4*)(bp + (long)(k0+kc+2)*FFH + n0 + rb*4);
            f32x4 c3 = *(const f32x4*)(bp + (long)(k0+kc+3)*FFH + n0 + rb*4);
            #pragma unroll
            for (int i = 0; i < 4; i++) {
                int r = rb*4 + i;
                if (SPLIT == 3) {
                    u16x4 hv, mv, lv;
                    unsigned short h,m,l;
                    split3(c0[i],h,m,l); hv[0]=h; mv[0]=m; lv[0]=l;
                    split3(c1[i],h,m,l); hv[1]=h; mv[1]=m; lv[1]=l;
                    split3(c2[i],h,m,l); hv[2]=h; mv[2]=m; lv[2]=l;
                    split3(c3[i],h,m,l); hv[3]=h; mv[3]=m; lv[3]=l;
                    *(u16x4*)&Bs[0][r*LDSS + kc] = hv;
                    *(u16x4*)&Bs[1][r*LDSS + kc] = mv;
                    *(u16x4*)&Bs[2][r*LDSS + kc] = lv;
                } else {
                    u16x4 hv = {f2bf(c0[i]), f2bf(c1[i]), f2bf(c2[i]), f2bf(c3[i])};
                    *(u16x4*)&Bs[0][r*LDSS + kc] = hv;
                }
            }
            __syncthreads();
            bf16x8 bf[SPLIT][4];
            #pragma unroll
            for (int s = 0; s < SPLIT; s++)
                #pragma unroll
                for (int ni = 0; ni < 4; ni++)
                    bf[s][ni] = *(const bf16x8*)&Bs[s][(wn + ni*16 + lr)*LDSS + lg*8];
            #pragma unroll
            for (int mi = 0; mi < 4; mi++) {
                bf16x8 ah = *(const bf16x8*)&As[0][(wm + mi*16 + lr)*LDSS + lg*8];
                #pragma unroll
                for (int ni = 0; ni < 4; ni++) {
                    f32x4 a = pass ? a3[mi][ni] : a1[mi][ni];
                    a = MFMA(ah, bf[0][ni], a);
                    if (SPLIT == 3) {
                        bf16x8 am = *(const bf16x8*)&As[1][(wm + mi*16 + lr)*LDSS + lg*8];
                        bf16x8 al = *(const bf16x8*)&As[2][(wm + mi*16 + lr)*LDSS + lg*8];
                        a = MFMA(ah, bf[1][ni], a);
                        a = MFMA(am, bf[0][ni], a);
                        a = MFMA(ah, bf[2][ni], a);
                        a = MFMA(am, bf[1][ni], a);
                        a = MFMA(al, bf[0][ni], a);
                    }
                    if (pass) a3[mi][ni] = a; else a1[mi][ni] = a;
                }
            }
            __syncthreads();
        }
    }
    #pragma unroll
    for (int mi = 0; mi < 4; mi++)
        #pragma unroll
        for (int r = 0; r < 4; r++) {
            int rowl = wm + mi*16 + lg*4 + r;
            if (m0 + rowl < cnt) {
                long crow = off + m0 + rowl;
                #pragma unroll
                for (int ni = 0; ni < 4; ni++) {
                    int col = n0 + wn + ni*16 + lr;
                    float v1 = a1[mi][ni][r];
                    float v3 = a3[mi][ni][r];
                    G[crow*FFH + col] = (v1 / (1.f + expf(-v1))) * v3;
                }
            }
        }
}

// ---------------- w2: A=g f32 x B f32, weighted atomic into h (64x128 tile) ----------------
template<int SPLIT>
__global__ __launch_bounds__(256, 3) void w2_kernel(
    const float* __restrict__ G, const float* __restrict__ W2, float* h,
    const int* __restrict__ rowidx, const float* __restrict__ wrow,
    const int* __restrict__ counts, const int* __restrict__ offsets)
{
    __shared__ __align__(16) unsigned short As[SPLIT][64*LDSS];
    __shared__ __align__(16) unsigned short Bs[SPLIT][128*LDSS];
    int e = blockIdx.z;
    int cnt = counts[e], off = offsets[e];
    int n0 = blockIdx.x*128, m0 = blockIdx.y*64;
    if (m0 >= cnt) return;
    const float* bp = W2 + (long)e * (FFH*D_MODEL);
    int tid = threadIdx.x, w = tid >> 6, lane = tid & 63;
    int wm = (w >> 1)*32, wn = (w & 1)*64;
    int lr = lane & 15, lg = lane >> 4;
    f32x4 zero = {0.f,0.f,0.f,0.f};
    f32x4 acc[2][4];
    #pragma unroll
    for (int mi = 0; mi < 2; mi++)
        #pragma unroll
        for (int ni = 0; ni < 4; ni++) acc[mi][ni] = zero;
    int rb = tid >> 3, kc = (tid & 7) << 2;

    for (int k0 = 0; k0 < FFH; k0 += 32) {
        #pragma unroll
        for (int p = 0; p < 2; p++) {
            int r = p*32 + rb;
            f32x4 vv = zero;
            if (m0 + r < cnt)
                vv = *(const f32x4*)(G + (long)(off + m0 + r)*FFH + k0 + kc);
            if (SPLIT == 3) {
                u16x4 hv, mv, lv;
                #pragma unroll
                for (int j = 0; j < 4; j++) { unsigned short h,m,l; split3(vv[j],h,m,l); hv[j]=h; mv[j]=m; lv[j]=l; }
                *(u16x4*)&As[0][r*LDSS + kc] = hv;
                *(u16x4*)&As[1][r*LDSS + kc] = mv;
                *(u16x4*)&As[2][r*LDSS + kc] = lv;
            } else {
                u16x4 hv;
                #pragma unroll
                for (int j = 0; j < 4; j++) hv[j] = f2bf(vv[j]);
                *(u16x4*)&As[0][r*LDSS + kc] = hv;
            }
        }
        {
            f32x4 c0 = *(const f32x4*)(bp + (long)(k0+kc+0)*D_MODEL + n0 + rb*4);
            f32x4 c1 = *(const f32x4*)(bp + (long)(k0+kc+1)*D_MODEL + n0 + rb*4);
            f32x4 c2 = *(const f32x4*)(bp + (long)(k0+kc+2)*D_MODEL + n0 + rb*4);
            f32x4 c3 = *(const f32x4*)(bp + (long)(k0+kc+3)*D_MODEL + n0 + rb*4);
            #pragma unroll
            for (int i = 0; i < 4; i++) {
                int r = rb*4 + i;
                if (SPLIT == 3) {
                    u16x4 hv, mv, lv;
                    unsigned short h,m,l;
                    split3(c0[i],h,m,l); hv[0]=h; mv[0]=m; lv[0]=l;
                    split3(c1[i],h,m,l); hv[1]=h; mv[1]=m; lv[1]=l;
                    split3(c2[i],h,m,l); hv[2]=h; mv[2]=m; lv[2]=l;
                    split3(c3[i],h,m,l); hv[3]=h; mv[3]=m; lv[3]=l;
                    *(u16x4*)&Bs[0][r*LDSS + kc] = hv;
                    *(u16x4*)&Bs[1][r*LDSS + kc] = mv;
                    *(u16x4*)&Bs[2][r*LDSS + kc] = lv;
                } else {
                    u16x4 hv = {f2bf(c0[i]), f2bf(c1[i]), f2bf(c2[i]), f2bf(c3[i])};
                    *(u16x4*)&Bs[0][r*LDSS + kc] = hv;
                }
            }
        }
        __syncthreads();
        bf16x8 bf[SPLIT][4];
        #pragma unroll
        for (int s = 0; s < SPLIT; s++)
            #pragma unroll
            for (int ni = 0; ni < 4; ni++)
                bf[s][ni] = *(const bf16x8*)&Bs[s][(wn + ni*16 + lr)*LDSS + lg*8];
        #pragma unroll
        for (int mi = 0; mi < 2; mi++) {
            bf16x8 ah = *(const bf16x8*)&As[0][(wm + mi*16 + lr)*LDSS + lg*8];
            #pragma unroll
            for (int ni = 0; ni < 4; ni++) {
                acc[mi][ni] = MFMA(ah, bf[0][ni], acc[mi][ni]);
                if (SPLIT == 3) {
                    bf16x8 am = *(const bf16x8*)&As[1][(wm + mi*16 + lr)*LDSS + lg*8];
                    bf16x8 al = *(const bf16x8*)&As[2][(wm + mi*16 + lr)*LDSS + lg*8];
                    acc[mi][ni] = MFMA(ah, bf[1][ni], acc[mi][ni]);
                    acc[mi][ni] = MFMA(am, bf[0][ni], acc[mi][ni]);
                    acc[mi][ni] = MFMA(ah, bf[2][ni], acc[mi][ni]);
                    acc[mi][ni] = MFMA(am, bf[1][ni], acc[mi][ni]);
                    acc[mi][ni] = MFMA(al, bf[0][ni], acc[mi][ni]);
                }
            }
        }
        __syncthreads();
    }
    #pragma unroll
    for (int mi = 0; mi < 2; mi++)
        #pragma unroll
        for (int r = 0; r < 4; r++) {
            int rowl = wm + mi*16 + lg*4 + r;
            if (m0 + rowl < cnt) {
                long crow = off + m0 + rowl;
                long n = rowidx[crow];
                float wgt = wrow[crow];
                #pragma unroll
                for (int ni = 0; ni < 4; ni++) {
                    int col = n0 + wn + ni*16 + lr;
                    atomicAdd(&h[n*D_MODEL + col], wgt * acc[mi][ni][r]);
                }
            }
        }
}

// ---------------- flash attention (causal, from planes, split-bf16 P) ----------------
__global__ __launch_bounds__(256) void attn_kernel(
    const unsigned short* __restrict__ q3, const unsigned short* __restrict__ k3,
    const unsigned short* __restrict__ v3, float* __restrict__ att)
{
    __shared__ __align__(16) unsigned short Qs[3][64*72];
    __shared__ __align__(16) unsigned short KP[3][2560];
    __shared__ __align__(16) unsigned short Vt[3][2560];
    int qt = blockIdx.x, bh = blockIdx.y;
    int b = bh >> 4, hh = bh & 15;
    int tid = threadIdx.x, w = tid >> 6, lane = tid & 63;
    int lr = lane & 15, lg = lane >> 4;
    int lrow = tid >> 4;
    int lcol = (tid & 15) << 2;

    #pragma unroll
    for (int p = 0; p < 4; p++) {
        int r = p*16 + lrow;
        long idx = (long)(b*SEQ + qt*64 + r)*D_MODEL + hh*64 + lcol;
        #pragma unroll
        for (int s = 0; s < 3; s++)
            *(u16x4*)&Qs[s][r*72 + lcol] = *(const u16x4*)(q3 + s*PSA + idx);
    }

    f32x4 zero = {0.f,0.f,0.f,0.f};
    f32x4 oacc[4] = {zero, zero, zero, zero};
    float mrun[4] = {-INFINITY,-INFINITY,-INFINITY,-INFINITY};
    float lrun[4] = {0.f,0.f,0.f,0.f};

    int ntile = 2*qt + 2;
    for (int jt = 0; jt < ntile; jt++) {
        #pragma unroll
        for (int p = 0; p < 2; p++) {
            int r = p*16 + lrow;
            long idx = (long)(b*SEQ + jt*32 + r)*D_MODEL + hh*64 + lcol;
            #pragma unroll
            for (int s = 0; s < 3; s++) {
                *(u16x4*)&KP[s][r*72 + lcol] = *(const u16x4*)(k3 + s*PSA + idx);
                u16x4 vv = *(const u16x4*)(v3 + s*PSA + idx);
                Vt[s][(lcol+0)*40 + r] = vv[0];
                Vt[s][(lcol+1)*40 + r] = vv[1];
                Vt[s][(lcol+2)*40 + r] = vv[2];
                Vt[s][(lcol+3)*40 + r] = vv[3];
            }
        }
        __syncthreads();

        f32x4 s[2] = {zero, zero};
        #pragma unroll
        for (int ks = 0; ks < 2; ks++) {
            bf16x8 qh = *(const bf16x8*)&Qs[0][(w*16 + lr)*72 + ks*32 + lg*8];
            bf16x8 qm = *(const bf16x8*)&Qs[1][(w*16 + lr)*72 + ks*32 + lg*8];
            bf16x8 ql = *(const bf16x8*)&Qs[2][(w*16 + lr)*72 + ks*32 + lg*8];
            #pragma unroll
            for (int ni = 0; ni < 2; ni++) {
                bf16x8 kh = *(const bf16x8*)&KP[0][(ni*16 + lr)*72 + ks*32 + lg*8];
                bf16x8 km = *(const bf16x8*)&KP[1][(ni*16 + lr)*72 + ks*32 + lg*8];
                bf16x8 kl = *(const bf16x8*)&KP[2][(ni*16 + lr)*72 + ks*32 + lg*8];
                s[ni] = MFMA(qh, kh, s[ni]);
                s[ni] = MFMA(qh, km, s[ni]);
                s[ni] = MFMA(qm, kh, s[ni]);
                s[ni] = MFMA(qh, kl, s[ni]);
                s[ni] = MFMA(qm, km, s[ni]);
                s[ni] = MFMA(ql, kh, s[ni]);
            }
        }
        __syncthreads();

        #pragma unroll
        for (int r = 0; r < 4; r++) {
            int qg = qt*64 + w*16 + lg*4 + r;
            float mx = -INFINITY;
            #pragma unroll
            for (int ni = 0; ni < 2; ni++) {
                int kg = jt*32 + ni*16 + lr;
                float val = s[ni][r] * 0.125f;
                if (kg > qg) val = -INFINITY;
                s[ni][r] = val;
                mx = fmaxf(mx, val);
            }
            #pragma unroll
            for (int dd = 1; dd < 16; dd <<= 1)
                mx = fmaxf(mx, __shfl_xor(mx, dd));
            float mnew  = fmaxf(mrun[r], mx);
            float alpha = expf(mrun[r] - mnew);
            float ps = 0.f;
            #pragma unroll
            for (int ni = 0; ni < 2; ni++) {
                float pv = expf(s[ni][r] - mnew);
                s[ni][r] = pv;
                ps += pv;
            }
            #pragma unroll
            for (int dd = 1; dd < 16; dd <<= 1)
                ps += __shfl_xor(ps, dd);
            lrun[r] = lrun[r] * alpha + ps;
            mrun[r] = mnew;
            #pragma unroll
            for (int d = 0; d < 4; d++) oacc[d][r] *= alpha;
            int prow = w*16 + lg*4 + r;
            #pragma unroll
            for (int ni = 0; ni < 2; ni++) {
                unsigned short h,m,l; split3(s[ni][r],h,m,l);
                KP[0][prow*40 + ni*16 + lr] = h;
                KP[1][prow*40 + ni*16 + lr] = m;
                KP[2][prow*40 + ni*16 + lr] = l;
            }
        }
        {
            bf16x8 ph = *(const bf16x8*)&KP[0][(w*16 + lr)*40 + lg*8];
            bf16x8 pm = *(const bf16x8*)&KP[1][(w*16 + lr)*40 + lg*8];
            bf16x8 pl = *(const bf16x8*)&KP[2][(w*16 + lr)*40 + lg*8];
            #pragma unroll
            for (int ni = 0; ni < 4; ni++) {
                bf16x8 vh = *(const bf16x8*)&Vt[0][(ni*16 + lr)*40 + lg*8];
                bf16x8 vm = *(const bf16x8*)&Vt[1][(ni*16 + lr)*40 + lg*8];
                bf16x8 vl = *(const bf16x8*)&Vt[2][(ni*16 + lr)*40 + lg*8];
                oacc[ni] = MFMA(ph, vh, oacc[ni]);
                oacc[ni] = MFMA(ph, vm, oacc[ni]);
                oacc[ni] = MFMA(pm, vh, oacc[ni]);
                oacc[ni] = MFMA(ph, vl, oacc[ni]);
                oacc[ni] = MFMA(pm, vm, oacc[ni]);
                oacc[ni] = MFMA(pl, vh, oacc[ni]);
            }
        }
        __syncthreads();
    }
    float* obase = att + ((long)(b*SEQ + qt*64) * D_MODEL + hh*64);
    #pragma unroll
    for (int r = 0; r < 4; r++) {
        float inv = 1.f / lrun[r];
        #pragma unroll
        for (int ni = 0; ni < 4; ni++)
            obase[(long)(w*16 + lg*4 + r) * D_MODEL + ni*16 + lr] = oacc[ni][r] * inv;
    }
}

// ---------------- logits: A plane0 x B=emb (BT), f32 out ----------------
__global__ __launch_bounds__(256) void logits_kernel(
    const unsigned short* __restrict__ A0, const float* __restrict__ Bmat, float* __restrict__ C)
{
    __shared__ __align__(16) unsigned short As[128*LDSS];
    __shared__ __align__(16) unsigned short Bs[128*LDSS];
    int n0 = blockIdx.y * 128;   // vocab
    int m0 = blockIdx.x * 128;   // tokens (fast dim -> emb panel L2 reuse)
    int tid = threadIdx.x, w = tid >> 6, lane = tid & 63;
    int wm = (w >> 1)*64, wn = (w & 1)*64;
    int lr = lane & 15, lg = lane >> 4;
    f32x4 zero = {0.f,0.f,0.f,0.f};
    f32x4 acc[4][4];
    #pragma unroll
    for (int mi = 0; mi < 4; mi++)
        #pragma unroll
        for (int ni = 0; ni < 4; ni++) acc[mi][ni] = zero;
    int rb = tid >> 3, kc = (tid & 7) << 2;
    for (int k0 = 0; k0 < D_MODEL; k0 += 32) {
        #pragma unroll
        for (int p = 0; p < 4; p++) {
            int r = p*32 + rb;
            *(u16x4*)&As[r*LDSS + kc] = *(const u16x4*)(A0 + (long)(m0+r)*D_MODEL + k0 + kc);
            f32x4 vv = *(const f32x4*)(Bmat + (long)(n0+r)*D_MODEL + k0 + kc);
            u16x4 hv;
            #pragma unroll
            for (int j = 0; j < 4; j++) hv[j] = f2bf(vv[j]);
            *(u16x4*)&Bs[r*LDSS + kc] = hv;
        }
        __syncthreads();
        bf16x8 bfv[4], af[4];
        #pragma unroll
        for (int ni = 0; ni < 4; ni++)
            bfv[ni] = *(const bf16x8*)&Bs[(wn + ni*16 + lr)*LDSS + lg*8];
        #pragma unroll
        for (int mi = 0; mi < 4; mi++)
            af[mi] = *(const bf16x8*)&As[(wm + mi*16 + lr)*LDSS + lg*8];
        #pragma unroll
        for (int mi = 0; mi < 4; mi++)
            #pragma unroll
            for (int ni = 0; ni < 4; ni++)
                acc[mi][ni] = MFMA(af[mi], bfv[ni], acc[mi][ni]);
        __syncthreads();
    }
    #pragma unroll
    for (int mi = 0; mi < 4; mi++)
        #pragma unroll
        for (int r = 0; r < 4; r++) {
            long row = m0 + wm + mi*16 + lg*4 + r;
            #pragma unroll
            for (int ni = 0; ni < 4; ni++) {
                int col = n0 + wn + ni*16 + lr;
                C[row*VOCAB + col] = acc[mi][ni][r];
            }
        }
}

// ---------------- small kernels ----------------
__global__ __launch_bounds__(256) void embed_kernel(const int* __restrict__ tok,
    const float* __restrict__ emb, float* __restrict__ h)
{
    int n = blockIdx.x;
    int c = threadIdx.x << 2;
    long t = tok[n];
    *(f32x4*)(h + (long)n*D_MODEL + c) = *(const f32x4*)(emb + t*D_MODEL + c);
}

__global__ __launch_bounds__(256) void ropetab_kernel(float* __restrict__ tab)
{
    int idx = blockIdx.x * 256 + threadIdx.x;
    if (idx >= SEQ * 32) return;
    int t = idx >> 5, i = idx & 31;
    double inv = pow(10000.0, -(double)(2*i) / 64.0);
    double ang = (double)t * inv;
    tab[idx*2]   = (float)cos(ang);
    tab[idx*2+1] = (float)sin(ang);
}

__global__ __launch_bounds__(256) void rope_kernel(unsigned short* q3, unsigned short* k3,
    const float* __restrict__ tab)
{
    int gid = blockIdx.x * 256 + threadIdx.x;
    if (gid >= NTOK * 128) return;
    int n  = gid >> 7;
    int c8 = (gid & 127) << 3;          // dim base, step 8
    int t  = n & (SEQ - 1);
    int i0 = (c8 & 63) >> 1;            // pair index base within head
    const float* tb = tab + (t*32 + i0)*2;
    long base = (long)n * D_MODEL + c8;
    #pragma unroll
    for (int mqk = 0; mqk < 2; mqk++) {
        unsigned short* P = mqk ? k3 : q3;
        float x[8];
        #pragma unroll
        for (int half = 0; half < 2; half++) {
            u16x4 xh = *(const u16x4*)(P + 0*PSA + base + half*4);
            u16x4 xm = *(const u16x4*)(P + 1*PSA + base + half*4);
            u16x4 xl = *(const u16x4*)(P + 2*PSA + base + half*4);
            #pragma unroll
            for (int j = 0; j < 4; j++)
                x[half*4+j] = bf2f(xh[j]) + bf2f(xm[j]) + bf2f(xl[j]);
        }
        #pragma unroll
        for (int p = 0; p < 4; p++) {
            float cs = tb[p*2], sn = tb[p*2+1];
            float xr = x[2*p], xi = x[2*p+1];
            x[2*p]   = xr*cs - xi*sn;
            x[2*p+1] = xr*sn + xi*cs;
        }
        #pragma unroll
        for (int half = 0; half < 2; half++) {
            u16x4 xh, xm, xl;
            #pragma unroll
            for (int j = 0; j < 4; j++) {
                unsigned short h,m,l; split3(x[half*4+j],h,m,l);
                xh[j]=h; xm[j]=m; xl[j]=l;
            }
            *(u16x4*)(P + 0*PSA + base + half*4) = xh;
            *(u16x4*)(P + 1*PSA + base + half*4) = xm;
            *(u16x4*)(P + 2*PSA + base + half*4) = xl;
        }
    }
}

__global__ __launch_bounds__(64) void gate_kernel(const unsigned short* __restrict__ xf3,
    const float* __restrict__ gw, int* __restrict__ counts,
    int* __restrict__ eid, float* __restrict__ wts, float* __restrict__ pbuf)
{
    int n = blockIdx.x;
    int lane = threadIdx.x;
    float acc[8] = {0,0,0,0,0,0,0,0};
    for (int d0 = lane*4; d0 < D_MODEL; d0 += 256) {
        long idx = (long)n*D_MODEL + d0;
        u16x4 xh = *(const u16x4*)(xf3 + 0*PSA + idx);
        u16x4 xm = *(const u16x4*)(xf3 + 1*PSA + idx);
        u16x4 xl = *(const u16x4*)(xf3 + 2*PSA + idx);
        #pragma unroll
        for (int j = 0; j < 4; j++) {
            float xv = bf2f(xh[j]) + bf2f(xm[j]) + bf2f(xl[j]);
            const float* g = gw + (d0+j) * 8;
            #pragma unroll
            for (int e = 0; e < 8; e++) acc[e] += xv * g[e];
        }
    }
    #pragma unroll
    for (int e = 0; e < 8; e++) {
        #pragma unroll
        for (int dd = 32; dd; dd >>= 1) acc[e] += __shfl_xor(acc[e], dd);
    }
    if (lane == 0) {
        float mx = acc[0];
        #pragma unroll
        for (int e = 1; e < 8; e++) mx = fmaxf(mx, acc[e]);
        float pe[8], ssum = 0.f;
        #pragma unroll
        for (int e = 0; e < 8; e++) { pe[e] = expf(acc[e] - mx); ssum += pe[e]; }
        float sinv = 1.f / ssum;
        #pragma unroll
        for (int e = 0; e < 8; e++) { pe[e] *= sinv; pbuf[n*8 + e] = pe[e]; }
        int e1 = 0;
        #pragma unroll
        for (int e = 1; e < 8; e++) if (pe[e] > pe[e1]) e1 = e;
        int e2 = -1;
        #pragma unroll
        for (int e = 0; e < 8; e++) if (e != e1 && (e2 < 0 || pe[e] > pe[e2])) e2 = e;
        float v1 = pe[e1], v2 = pe[e2];
        float wsum = v1 + v2 + 1e-8f;
        eid[n*2] = e1; eid[n*2+1] = e2;
        wts[n*2] = v1 / wsum; wts[n*2+1] = v2 / wsum;
        atomicAdd(counts + e1, 1);
        atomicAdd(counts + e2, 1);
    }
}

__global__ __launch_bounds__(64) void scan_kernel(const int* __restrict__ counts,
    int* __restrict__ offs, int* __restrict__ cursor,
    const float* __restrict__ pbuf, float* __restrict__ aux)
{
    int t = threadIdx.x;
    int e = t & 7, c = t >> 3;
    float s = 0.f;
    for (int n = 0; n < NTOK/8; n++)
        s += pbuf[(c*(NTOK/8) + n)*8 + e];
    #pragma unroll
    for (int dd = 8; dd < 64; dd <<= 1) s += __shfl_xor(s, dd);
    __shared__ float red[8];
    if (t < 8) red[t] = s;
    __syncthreads();
    if (t == 0) {
        int o = 0; float a = 0.f;
        for (int k = 0; k < 8; k++) {
            offs[k] = o; cursor[k] = o; o += counts[k];
            a += (float)counts[k] * red[k];
        }
        aux[0] += 8.f * a / ((float)NTOK * (float)NTOK);
    }
}

__global__ __launch_bounds__(256) void assign_kernel(const int* __restrict__ eid,
    const float* __restrict__ wts, int* __restrict__ cursor,
    int* __restrict__ rowidx, float* __restrict__ wrow)
{
    int n = blockIdx.x * 256 + threadIdx.x;
    if (n >= NTOK) return;
    #pragma unroll
    for (int s = 0; s < 2; s++) {
        int e = eid[n*2 + s];
        int p = atomicAdd(cursor + e, 1);
        rowidx[p] = n;
        wrow[p] = wts[n*2 + s];
    }
}

__global__ void write_aux_kernel(float* __restrict__ out, const float* __restrict__ aux)
{
    if (threadIdx.x == 0 && blockIdx.x == 0)
        out[(long)NTOK * VOCAB] = aux[0];
}

// ---------------- launch ----------------
extern "C" void kernel_launch(void* const* d_in, const int* in_sizes, int n_in,
                              void* d_out, int out_size, void* d_ws, size_t ws_size,
                              hipStream_t stream)
{
    const int*   tokens = (const int*)d_in[0];
    const float* emb    = (const float*)d_in[1];
    const float* anw    = (const float*)d_in[2];
    const float* wq     = (const float*)d_in[3];
    const float* wk     = (const float*)d_in[4];
    const float* wv     = (const float*)d_in[5];
    const float* wo     = (const float*)d_in[6];
    const float* fnw    = (const float*)d_in[7];
    const float* gw     = (const float*)d_in[8];
    const float* w1     = (const float*)d_in[9];
    const float* w2     = (const float*)d_in[10];
    const float* w3     = (const float*)d_in[11];
    const float* finw   = (const float*)d_in[12];
    float* out = (float*)d_out;

    char* W = (char*)d_ws;
    const size_t MB = 1024u * 1024u;
    // ctrl block [0, 1MB)
    int*   counts = (int*)(W + 0);
    int*   offs   = (int*)(W + 64);
    int*   cursor = (int*)(W + 128);
    float* aux    = (float*)(W + 192);
    int*   eid    = (int*)(W + 4096);
    float* wts    = (float*)(W + 4096 + 16384);
    int*   rowix  = (int*)(W + 4096 + 32768);
    float* wrow   = (float*)(W + 4096 + 49152);
    float* pbuf   = (float*)(W + 4096 + 65536);
    float* rtab   = (float*)(W + 4096 + 131072 + 65536);
    // big buffers — lifetimes:
    //   wbuf3 [57,63) live only between its wsplitT and qkv (per projection)
    //   att   [57,65) live attn->wo (wbuf3 dead)
    //   g     [21,53) MoE phase (qkv3 dead)
    // peak = 65 MB
    float*          h    = (float*)(W + 1*MB);                   // [1,9)
    unsigned short* hn3  = (unsigned short*)(W + 9*MB);          // [9,21)
    unsigned short* qkv3 = (unsigned short*)(W + 21*MB);         // [21,57): 9 planes x 4MB
    unsigned short* wbuf3= (unsigned short*)(W + 57*MB);         // [57,63)
    float*          att  = (float*)(W + 57*MB);                  // [57,65)
    float*          g    = (float*)(W + 21*MB);                  // MoE phase [21,53)
    unsigned short* q3 = qkv3;
    unsigned short* k3 = qkv3 + 3*PSA;
    unsigned short* v3 = qkv3 + 6*PSA;

    hipMemsetAsync(W, 0, 256, stream);
    ropetab_kernel<<<(SEQ*32 + 255)/256, 256, 0, stream>>>(rtab);
    embed_kernel<<<NTOK, 256, 0, stream>>>(tokens, emb, h);

    for (int l = 0; l < 2; l++) {
        const float* wql = wq + (size_t)l*D_MODEL*D_MODEL;
        const float* wkl = wk + (size_t)l*D_MODEL*D_MODEL;
        const float* wvl = wv + (size_t)l*D_MODEL*D_MODEL;
        const float* wol = wo + (size_t)l*D_MODEL*D_MODEL;

        rmsnorm_kernel<<<NTOK, 256, 0, stream>>>(h, anw + (size_t)l*D_MODEL, hn3);
        // sequential per-projection: wsplitT fills wbuf3, qkv consumes it (same stream => ordered)
        const float* wsrc[3] = {wql, wkl, wvl};
        for (int z = 0; z < 3; z++) {
            wsplitT_kernel<<<dim3(16, 16), 256, 0, stream>>>(wsrc[z], wbuf3);
            qkv_kernel<<<dim3(D_MODEL/128, NTOK/64), 256, 0, stream>>>(hn3, wbuf3, qkv3 + (long)z*3*PSA);
        }
        rope_kernel<<<(NTOK*128 + 255)/256, 256, 0, stream>>>(q3, k3, rtab);
        attn_kernel<<<dim3(SEQ/64, BATCH*NHEADS), 256, 0, stream>>>(q3, k3, v3, att);
        wo_kernel<<<dim3(D_MODEL/64, NTOK/64), 256, 0, stream>>>(att, wol, h);

        rmsnorm_kernel<<<NTOK, 256, 0, stream>>>(h, fnw + (size_t)l*D_MODEL, hn3);
        hipMemsetAsync(W, 0, 160, stream);   // counts/offs/cursor (aux preserved @192)
        gate_kernel<<<NTOK, 64, 0, stream>>>(hn3, gw + (size_t)l*D_MODEL*NEXP, counts, eid, wts, pbuf);
        scan_kernel<<<1, 64, 0, stream>>>(counts, offs, cursor, pbuf, aux);
        assign_kernel<<<(NTOK + 255)/256, 256, 0, stream>>>(eid, wts, cursor, rowix, wrow);

        const float* w1l = w1 + (size_t)l*NEXP*D_MODEL*FFH;
        const float* w3l = w3 + (size_t)l*NEXP*D_MODEL*FFH;
        const float* w2l = w2 + (size_t)l*NEXP*FFH*D_MODEL;
        dim3 g13(FFH/128, 2*NTOK/128, NEXP);
        dim3 g2d(D_MODEL/128, 2*NTOK/64, NEXP);
        if (l == 0) {
            moe13_kernel<3><<<g13, 256, 0, stream>>>(hn3, w1l, w3l, g, rowix, counts, offs);
            w2_kernel<3><<<g2d, 256, 0, stream>>>(g, w2l, h, rowix, wrow, counts, offs);
        } else {
            moe13_kernel<1><<<g13, 256, 0, stream>>>(hn3, w1l, w3l, g, rowix, counts, offs);
            w2_kernel<1><<<g2d, 256, 0, stream>>>(g, w2l, h, rowix, wrow, counts, offs);
        }
    }

    rmsnorm_kernel<<<NTOK, 256, 0, stream>>>(h, finw, hn3);
    logits_kernel<<<dim3(NTOK/128, VOCAB/128), 256, 0, stream>>>(hn3, emb, out);
    write_aux_kernel<<<1, 1, 0, stream>>>(out, aux);
}

// Round 7
// 2055.704 us; speedup vs baseline: 3.6223x; 1.1620x over previous
//
#include <hip/hip_runtime.h>
#include <hip/hip_bf16.h>
#include <math.h>

#define D_MODEL 1024
#define NHEADS  16
#define HDIM    64
#define NEXP    8
#define FFH     2048
#define BATCH   2
#define SEQ     1024
#define NTOK    2048
#define VOCAB   32000
#define LDSS    40   // LDS row stride in shorts (80 B, 16B-aligned, conflict-light)

typedef __attribute__((ext_vector_type(4))) float f32x4;
typedef __attribute__((ext_vector_type(2))) float f32x2;
typedef __attribute__((ext_vector_type(8))) __bf16 bf16x8;
typedef __attribute__((ext_vector_type(4))) unsigned short u16x4;

__device__ __forceinline__ unsigned short f2bf(float f) {
    union { float f; unsigned u; } v; v.f = f;
    unsigned r = v.u + 0x7FFFu + ((v.u >> 16) & 1u);
    return (unsigned short)(r >> 16);
}
__device__ __forceinline__ float bf2f(unsigned short u) {
    union { unsigned u; float f; } v; v.u = ((unsigned)u) << 16; return v.f;
}
__device__ __forceinline__ void split3(float x, unsigned short& h, unsigned short& m, unsigned short& l) {
    h = f2bf(x);
    float r1 = x - bf2f(h);
    m = f2bf(r1);
    float r2 = r1 - bf2f(m);
    l = f2bf(r2);
}

#define MFMA(a, b, c) __builtin_amdgcn_mfma_f32_16x16x32_bf16((a), (b), (c), 0, 0, 0)

#define PSA ((long)NTOK * D_MODEL)       // activation plane stride
#define PSW ((long)D_MODEL * D_MODEL)    // weight plane stride

// ---------------- rmsnorm -> 3 bf16 planes ----------------
__global__ __launch_bounds__(256) void rmsnorm_kernel(const float* __restrict__ x,
    const float* __restrict__ wt, unsigned short* __restrict__ out3)
{
    __shared__ float red[4];
    int n = blockIdx.x;
    int c = threadIdx.x << 2;
    f32x4 v = *(const f32x4*)(x + (long)n*D_MODEL + c);
    float ss = v.x*v.x + v.y*v.y + v.z*v.z + v.w*v.w;
    #pragma unroll
    for (int dd = 32; dd; dd >>= 1) ss += __shfl_xor(ss, dd);
    if ((threadIdx.x & 63) == 0) red[threadIdx.x >> 6] = ss;
    __syncthreads();
    float tot = red[0] + red[1] + red[2] + red[3];
    float rms = rsqrtf(tot * (1.f / D_MODEL) + 1e-6f);
    f32x4 wv = *(const f32x4*)(wt + c);
    f32x4 o = v * rms;
    o = o * wv;
    u16x4 hv, mv, lv;
    #pragma unroll
    for (int j = 0; j < 4; j++) { unsigned short h,m,l; split3(o[j],h,m,l); hv[j]=h; mv[j]=m; lv[j]=l; }
    long idx = (long)n*D_MODEL + c;
    *(u16x4*)(out3 + 0*PSA + idx) = hv;
    *(u16x4*)(out3 + 1*PSA + idx) = mv;
    *(u16x4*)(out3 + 2*PSA + idx) = lv;
}

// ---------------- weight transpose+split: W[K][N] f32 -> out[p][N][K] bf16, 3 weights via z ----------------
__global__ __launch_bounds__(256) void wsplitT_kernel(
    const float* __restrict__ wqs, const float* __restrict__ wks, const float* __restrict__ wvs,
    unsigned short* __restrict__ oq, unsigned short* __restrict__ ok, unsigned short* __restrict__ ov)
{
    __shared__ float t[64][65];
    int k0 = blockIdx.x*64, n0 = blockIdx.y*64, z = blockIdx.z;
    const float* src = (z==0) ? wqs : (z==1) ? wks : wvs;
    unsigned short* dst = (z==0) ? oq : (z==1) ? ok : ov;
    int tid = threadIdx.x;
    int a = tid & 63, g = tid >> 6;
    #pragma unroll 4
    for (int i = 0; i < 16; i++) {
        int k = g*16 + i;
        t[k][a] = src[(long)(k0+k)*D_MODEL + n0 + a];
    }
    __syncthreads();
    #pragma unroll 4
    for (int i = 0; i < 16; i++) {
        int n = g*16 + i;
        float v = t[a][n];               // k = a
        unsigned short h,m,l; split3(v,h,m,l);
        long idx = (long)(n0+n)*D_MODEL + k0 + a;
        dst[0*PSW + idx] = h;
        dst[1*PSW + idx] = m;
        dst[2*PSW + idx] = l;
    }
}

// ---------------- QKV MULTI: A planes x W planes -> f32 out (64x64 tile, 4 blk/CU) ----------------
__global__ __launch_bounds__(256, 4) void qkv_kernel(
    const unsigned short* __restrict__ A3,
    const unsigned short* __restrict__ Wq3, const unsigned short* __restrict__ Wk3,
    const unsigned short* __restrict__ Wv3,
    float* __restrict__ qf, float* __restrict__ kf, float* __restrict__ vf)
{
    __shared__ __align__(16) unsigned short As[3][64*LDSS];
    __shared__ __align__(16) unsigned short Bs[3][64*LDSS];
    int z = blockIdx.z;
    const unsigned short* B3 = (z==0) ? Wq3 : (z==1) ? Wk3 : Wv3;
    float* out = (z==0) ? qf : (z==1) ? kf : vf;
    int n0 = blockIdx.x*64, m0 = blockIdx.y*64;
    int tid = threadIdx.x, w = tid >> 6, lane = tid & 63;
    int wm = (w >> 1)*32, wn = (w & 1)*32;
    int lr = lane & 15, lg = lane >> 4;
    f32x4 zero = {0.f,0.f,0.f,0.f};
    f32x4 acc[2][2];
    #pragma unroll
    for (int mi = 0; mi < 2; mi++)
        #pragma unroll
        for (int ni = 0; ni < 2; ni++) acc[mi][ni] = zero;
    int rb = tid >> 3, kc = (tid & 7) << 2;

    for (int k0 = 0; k0 < D_MODEL; k0 += 32) {
        #pragma unroll
        for (int p = 0; p < 2; p++) {
            int r = p*32 + rb;
            #pragma unroll
            for (int s = 0; s < 3; s++) {
                *(u16x4*)&As[s][r*LDSS + kc] = *(const u16x4*)(A3 + s*PSA + (long)(m0+r)*D_MODEL + k0 + kc);
                *(u16x4*)&Bs[s][r*LDSS + kc] = *(const u16x4*)(B3 + s*PSW + (long)(n0+r)*D_MODEL + k0 + kc);
            }
        }
        __syncthreads();
        bf16x8 bf[3][2];
        #pragma unroll
        for (int s = 0; s < 3; s++)
            #pragma unroll
            for (int ni = 0; ni < 2; ni++)
                bf[s][ni] = *(const bf16x8*)&Bs[s][(wn + ni*16 + lr)*LDSS + lg*8];
        #pragma unroll
        for (int mi = 0; mi < 2; mi++) {
            bf16x8 ah = *(const bf16x8*)&As[0][(wm + mi*16 + lr)*LDSS + lg*8];
            bf16x8 am = *(const bf16x8*)&As[1][(wm + mi*16 + lr)*LDSS + lg*8];
            bf16x8 al = *(const bf16x8*)&As[2][(wm + mi*16 + lr)*LDSS + lg*8];
            #pragma unroll
            for (int ni = 0; ni < 2; ni++) {
                acc[mi][ni] = MFMA(ah, bf[0][ni], acc[mi][ni]);
                acc[mi][ni] = MFMA(ah, bf[1][ni], acc[mi][ni]);
                acc[mi][ni] = MFMA(am, bf[0][ni], acc[mi][ni]);
                acc[mi][ni] = MFMA(ah, bf[2][ni], acc[mi][ni]);
                acc[mi][ni] = MFMA(am, bf[1][ni], acc[mi][ni]);
                acc[mi][ni] = MFMA(al, bf[0][ni], acc[mi][ni]);
            }
        }
        __syncthreads();
    }
    #pragma unroll
    for (int mi = 0; mi < 2; mi++)
        #pragma unroll
        for (int r = 0; r < 4; r++) {
            long row = m0 + wm + mi*16 + lg*4 + r;
            #pragma unroll
            for (int ni = 0; ni < 2; ni++) {
                int col = n0 + wn + ni*16 + lr;
                out[row*D_MODEL + col] = acc[mi][ni][r];
            }
        }
}

// ---------------- WO: A f32 x B f32 (both split in-kernel), h += (64x64 tile) ----------------
__global__ __launch_bounds__(256, 3) void wo_kernel(
    const float* __restrict__ A, const float* __restrict__ B, float* h)
{
    __shared__ __align__(16) unsigned short As[3][64*LDSS];
    __shared__ __align__(16) unsigned short Bs[3][64*LDSS];
    int n0 = blockIdx.x*64, m0 = blockIdx.y*64;
    int tid = threadIdx.x, w = tid >> 6, lane = tid & 63;
    int wm = (w >> 1)*32, wn = (w & 1)*32;
    int lr = lane & 15, lg = lane >> 4;
    f32x4 zero = {0.f,0.f,0.f,0.f};
    f32x4 acc[2][2];
    #pragma unroll
    for (int mi = 0; mi < 2; mi++)
        #pragma unroll
        for (int ni = 0; ni < 2; ni++) acc[mi][ni] = zero;
    int rb = tid >> 3, kc = (tid & 7) << 2;      // A staging
    int nb = (tid & 31) << 1, kb = (tid >> 5) << 2;  // B staging

    for (int k0 = 0; k0 < D_MODEL; k0 += 32) {
        #pragma unroll
        for (int p = 0; p < 2; p++) {
            int r = p*32 + rb;
            f32x4 vv = *(const f32x4*)(A + (long)(m0+r)*D_MODEL + k0 + kc);
            u16x4 hv, mv, lv;
            #pragma unroll
            for (int j = 0; j < 4; j++) { unsigned short h,m,l; split3(vv[j],h,m,l); hv[j]=h; mv[j]=m; lv[j]=l; }
            *(u16x4*)&As[0][r*LDSS + kc] = hv;
            *(u16x4*)&As[1][r*LDSS + kc] = mv;
            *(u16x4*)&As[2][r*LDSS + kc] = lv;
        }
        {
            f32x2 c0 = *(const f32x2*)(B + (long)(k0+kb+0)*D_MODEL + n0 + nb);
            f32x2 c1 = *(const f32x2*)(B + (long)(k0+kb+1)*D_MODEL + n0 + nb);
            f32x2 c2 = *(const f32x2*)(B + (long)(k0+kb+2)*D_MODEL + n0 + nb);
            f32x2 c3 = *(const f32x2*)(B + (long)(k0+kb+3)*D_MODEL + n0 + nb);
            #pragma unroll
            for (int i = 0; i < 2; i++) {
                int r = nb + i;
                u16x4 hv, mv, lv;
                unsigned short h,m,l;
                split3(c0[i],h,m,l); hv[0]=h; mv[0]=m; lv[0]=l;
                split3(c1[i],h,m,l); hv[1]=h; mv[1]=m; lv[1]=l;
                split3(c2[i],h,m,l); hv[2]=h; mv[2]=m; lv[2]=l;
                split3(c3[i],h,m,l); hv[3]=h; mv[3]=m; lv[3]=l;
                *(u16x4*)&Bs[0][r*LDSS + kb] = hv;
                *(u16x4*)&Bs[1][r*LDSS + kb] = mv;
                *(u16x4*)&Bs[2][r*LDSS + kb] = lv;
            }
        }
        __syncthreads();
        bf16x8 bf[3][2];
        #pragma unroll
        for (int s = 0; s < 3; s++)
            #pragma unroll
            for (int ni = 0; ni < 2; ni++)
                bf[s][ni] = *(const bf16x8*)&Bs[s][(wn + ni*16 + lr)*LDSS + lg*8];
        #pragma unroll
        for (int mi = 0; mi < 2; mi++) {
            bf16x8 ah = *(const bf16x8*)&As[0][(wm + mi*16 + lr)*LDSS + lg*8];
            bf16x8 am = *(const bf16x8*)&As[1][(wm + mi*16 + lr)*LDSS + lg*8];
            bf16x8 al = *(const bf16x8*)&As[2][(wm + mi*16 + lr)*LDSS + lg*8];
            #pragma unroll
            for (int ni = 0; ni < 2; ni++) {
                acc[mi][ni] = MFMA(ah, bf[0][ni], acc[mi][ni]);
                acc[mi][ni] = MFMA(ah, bf[1][ni], acc[mi][ni]);
                acc[mi][ni] = MFMA(am, bf[0][ni], acc[mi][ni]);
                acc[mi][ni] = MFMA(ah, bf[2][ni], acc[mi][ni]);
                acc[mi][ni] = MFMA(am, bf[1][ni], acc[mi][ni]);
                acc[mi][ni] = MFMA(al, bf[0][ni], acc[mi][ni]);
            }
        }
        __syncthreads();
    }
    #pragma unroll
    for (int mi = 0; mi < 2; mi++)
        #pragma unroll
        for (int r = 0; r < 4; r++) {
            long row = m0 + wm + mi*16 + lg*4 + r;
            #pragma unroll
            for (int ni = 0; ni < 2; ni++) {
                int col = n0 + wn + ni*16 + lr;
                h[row*D_MODEL + col] += acc[mi][ni][r];
            }
        }
}

// ---------------- fused MoE w1/w3: 64x128 tile, 3 blk/CU ----------------
template<int SPLIT>
__global__ __launch_bounds__(256, 3) void moe13_kernel(
    const unsigned short* __restrict__ A3, const float* __restrict__ W1,
    const float* __restrict__ W3, float* __restrict__ G,
    const int* __restrict__ rowidx, const int* __restrict__ counts,
    const int* __restrict__ offsets)
{
    __shared__ __align__(16) unsigned short As[SPLIT][64*LDSS];
    __shared__ __align__(16) unsigned short Bs[SPLIT][128*LDSS];
    int e = blockIdx.z;
    int cnt = counts[e], off = offsets[e];
    int n0 = blockIdx.x*128, m0 = blockIdx.y*64;
    if (m0 >= cnt) return;
    const float* b1p = W1 + (long)e * (D_MODEL*FFH);
    const float* b3p = W3 + (long)e * (D_MODEL*FFH);
    int tid = threadIdx.x, w = tid >> 6, lane = tid & 63;
    int wm = (w >> 1)*32, wn = (w & 1)*64;
    int lr = lane & 15, lg = lane >> 4;
    f32x4 zero = {0.f,0.f,0.f,0.f};
    f32x4 a1[2][4], a3[2][4];
    #pragma unroll
    for (int mi = 0; mi < 2; mi++)
        #pragma unroll
        for (int ni = 0; ni < 4; ni++) { a1[mi][ni] = zero; a3[mi][ni] = zero; }
    int rb = tid >> 3, kc = (tid & 7) << 2;

    for (int k0 = 0; k0 < D_MODEL; k0 += 32) {
        #pragma unroll
        for (int p = 0; p < 2; p++) {
            int r = p*32 + rb;
            u16x4 z4 = {0,0,0,0};
            if (m0 + r < cnt) {
                long arow = (long)rowidx[off + m0 + r];
                #pragma unroll
                for (int s = 0; s < SPLIT; s++)
                    *(u16x4*)&As[s][r*LDSS + kc] = *(const u16x4*)(A3 + s*PSA + arow*D_MODEL + k0 + kc);
            } else {
                #pragma unroll
                for (int s = 0; s < SPLIT; s++)
                    *(u16x4*)&As[s][r*LDSS + kc] = z4;
            }
        }
        #pragma unroll
        for (int pass = 0; pass < 2; pass++) {
            const float* bp = pass ? b3p : b1p;
            f32x4 c0 = *(const f32x4*)(bp + (long)(k0+kc+0)*FFH + n0 + rb*4);
            f32x4 c1 = *(const f32x4*)(bp + (long)(k0+kc+1)*FFH + n0 + rb*4);
            f32x4 c2 = *(const f32x4*)(bp + (long)(k0+kc+2)*FFH + n0 + rb*4);
            f32x4 c3 = *(const f32x4*)(bp + (long)(k0+kc+3)*FFH + n0 + rb*4);
            #pragma unroll
            for (int i = 0; i < 4; i++) {
                int r = rb*4 + i;
                if (SPLIT == 3) {
                    u16x4 hv, mv, lv;
                    unsigned short h,m,l;
                    split3(c0[i],h,m,l); hv[0]=h; mv[0]=m; lv[0]=l;
                    split3(c1[i],h,m,l); hv[1]=h; mv[1]=m; lv[1]=l;
                    split3(c2[i],h,m,l); hv[2]=h; mv[2]=m; lv[2]=l;
                    split3(c3[i],h,m,l); hv[3]=h; mv[3]=m; lv[3]=l;
                    *(u16x4*)&Bs[0][r*LDSS + kc] = hv;
                    *(u16x4*)&Bs[1][r*LDSS + kc] = mv;
                    *(u16x4*)&Bs[2][r*LDSS + kc] = lv;
                } else {
                    u16x4 hv = {f2bf(c0[i]), f2bf(c1[i]), f2bf(c2[i]), f2bf(c3[i])};
                    *(u16x4*)&Bs[0][r*LDSS + kc] = hv;
                }
            }
            __syncthreads();
            bf16x8 bf[SPLIT][4];
            #pragma unroll
            for (int s = 0; s < SPLIT; s++)
                #pragma unroll
                for (int ni = 0; ni < 4; ni++)
                    bf[s][ni] = *(const bf16x8*)&Bs[s][(wn + ni*16 + lr)*LDSS + lg*8];
            #pragma unroll
            for (int mi = 0; mi < 2; mi++) {
                bf16x8 ah = *(const bf16x8*)&As[0][(wm + mi*16 + lr)*LDSS + lg*8];
                #pragma unroll
                for (int ni = 0; ni < 4; ni++) {
                    f32x4 a = pass ? a3[mi][ni] : a1[mi][ni];
                    a = MFMA(ah, bf[0][ni], a);
                    if (SPLIT == 3) {
                        bf16x8 am = *(const bf16x8*)&As[1][(wm + mi*16 + lr)*LDSS + lg*8];
                        bf16x8 al = *(const bf16x8*)&As[2][(wm + mi*16 + lr)*LDSS + lg*8];
                        a = MFMA(ah, bf[1][ni], a);
                        a = MFMA(am, bf[0][ni], a);
                        a = MFMA(ah, bf[2][ni], a);
                        a = MFMA(am, bf[1][ni], a);
                        a = MFMA(al, bf[0][ni], a);
                    }
                    if (pass) a3[mi][ni] = a; else a1[mi][ni] = a;
                }
            }
            __syncthreads();
        }
    }
    #pragma unroll
    for (int mi = 0; mi < 2; mi++)
        #pragma unroll
        for (int r = 0; r < 4; r++) {
            int rowl = wm + mi*16 + lg*4 + r;
            if (m0 + rowl < cnt) {
                long crow = off + m0 + rowl;
                #pragma unroll
                for (int ni = 0; ni < 4; ni++) {
                    int col = n0 + wn + ni*16 + lr;
                    float v1 = a1[mi][ni][r];
                    float v3 = a3[mi][ni][r];
                    G[crow*FFH + col] = (v1 / (1.f + expf(-v1))) * v3;
                }
            }
        }
}

// ---------------- w2: 64x64 tile, 4 blk/CU, weighted atomic into h ----------------
template<int SPLIT>
__global__ __launch_bounds__(256, 4) void w2_kernel(
    const float* __restrict__ G, const float* __restrict__ W2, float* h,
    const int* __restrict__ rowidx, const float* __restrict__ wrow,
    const int* __restrict__ counts, const int* __restrict__ offsets)
{
    __shared__ __align__(16) unsigned short As[SPLIT][64*LDSS];
    __shared__ __align__(16) unsigned short Bs[SPLIT][64*LDSS];
    int e = blockIdx.z;
    int cnt = counts[e], off = offsets[e];
    int n0 = blockIdx.x*64, m0 = blockIdx.y*64;
    if (m0 >= cnt) return;
    const float* bp = W2 + (long)e * (FFH*D_MODEL);
    int tid = threadIdx.x, w = tid >> 6, lane = tid & 63;
    int wm = (w >> 1)*32, wn = (w & 1)*32;
    int lr = lane & 15, lg = lane >> 4;
    f32x4 zero = {0.f,0.f,0.f,0.f};
    f32x4 acc[2][2];
    #pragma unroll
    for (int mi = 0; mi < 2; mi++)
        #pragma unroll
        for (int ni = 0; ni < 2; ni++) acc[mi][ni] = zero;
    int rb = tid >> 3, kc = (tid & 7) << 2;      // A staging
    int nb = (tid & 31) << 1, kb = (tid >> 5) << 2;  // B staging

    for (int k0 = 0; k0 < FFH; k0 += 32) {
        #pragma unroll
        for (int p = 0; p < 2; p++) {
            int r = p*32 + rb;
            f32x4 vv = zero;
            if (m0 + r < cnt)
                vv = *(const f32x4*)(G + (long)(off + m0 + r)*FFH + k0 + kc);
            if (SPLIT == 3) {
                u16x4 hv, mv, lv;
                #pragma unroll
                for (int j = 0; j < 4; j++) { unsigned short h,m,l; split3(vv[j],h,m,l); hv[j]=h; mv[j]=m; lv[j]=l; }
                *(u16x4*)&As[0][r*LDSS + kc] = hv;
                *(u16x4*)&As[1][r*LDSS + kc] = mv;
                *(u16x4*)&As[2][r*LDSS + kc] = lv;
            } else {
                u16x4 hv;
                #pragma unroll
                for (int j = 0; j < 4; j++) hv[j] = f2bf(vv[j]);
                *(u16x4*)&As[0][r*LDSS + kc] = hv;
            }
        }
        {
            f32x2 c0 = *(const f32x2*)(bp + (long)(k0+kb+0)*D_MODEL + n0 + nb);
            f32x2 c1 = *(const f32x2*)(bp + (long)(k0+kb+1)*D_MODEL + n0 + nb);
            f32x2 c2 = *(const f32x2*)(bp + (long)(k0+kb+2)*D_MODEL + n0 + nb);
            f32x2 c3 = *(const f32x2*)(bp + (long)(k0+kb+3)*D_MODEL + n0 + nb);
            #pragma unroll
            for (int i = 0; i < 2; i++) {
                int r = nb + i;
                if (SPLIT == 3) {
                    u16x4 hv, mv, lv;
                    unsigned short h,m,l;
                    split3(c0[i],h,m,l); hv[0]=h; mv[0]=m; lv[0]=l;
                    split3(c1[i],h,m,l); hv[1]=h; mv[1]=m; lv[1]=l;
                    split3(c2[i],h,m,l); hv[2]=h; mv[2]=m; lv[2]=l;
                    split3(c3[i],h,m,l); hv[3]=h; mv[3]=m; lv[3]=l;
                    *(u16x4*)&Bs[0][r*LDSS + kb] = hv;
                    *(u16x4*)&Bs[1][r*LDSS + kb] = mv;
                    *(u16x4*)&Bs[2][r*LDSS + kb] = lv;
                } else {
                    u16x4 hv = {f2bf(c0[i]), f2bf(c1[i]), f2bf(c2[i]), f2bf(c3[i])};
                    *(u16x4*)&Bs[0][r*LDSS + kb] = hv;
                }
            }
        }
        __syncthreads();
        bf16x8 bf[SPLIT][2];
        #pragma unroll
        for (int s = 0; s < SPLIT; s++)
            #pragma unroll
            for (int ni = 0; ni < 2; ni++)
                bf[s][ni] = *(const bf16x8*)&Bs[s][(wn + ni*16 + lr)*LDSS + lg*8];
        #pragma unroll
        for (int mi = 0; mi < 2; mi++) {
            bf16x8 ah = *(const bf16x8*)&As[0][(wm + mi*16 + lr)*LDSS + lg*8];
            #pragma unroll
            for (int ni = 0; ni < 2; ni++) {
                acc[mi][ni] = MFMA(ah, bf[0][ni], acc[mi][ni]);
                if (SPLIT == 3) {
                    bf16x8 am = *(const bf16x8*)&As[1][(wm + mi*16 + lr)*LDSS + lg*8];
                    bf16x8 al = *(const bf16x8*)&As[2][(wm + mi*16 + lr)*LDSS + lg*8];
                    acc[mi][ni] = MFMA(ah, bf[1][ni], acc[mi][ni]);
                    acc[mi][ni] = MFMA(am, bf[0][ni], acc[mi][ni]);
                    acc[mi][ni] = MFMA(ah, bf[2][ni], acc[mi][ni]);
                    acc[mi][ni] = MFMA(am, bf[1][ni], acc[mi][ni]);
                    acc[mi][ni] = MFMA(al, bf[0][ni], acc[mi][ni]);
                }
            }
        }
        __syncthreads();
    }
    #pragma unroll
    for (int mi = 0; mi < 2; mi++)
        #pragma unroll
        for (int r = 0; r < 4; r++) {
            int rowl = wm + mi*16 + lg*4 + r;
            if (m0 + rowl < cnt) {
                long crow = off + m0 + rowl;
                long n = rowidx[crow];
                float wgt = wrow[crow];
                #pragma unroll
                for (int ni = 0; ni < 2; ni++) {
                    int col = n0 + wn + ni*16 + lr;
                    atomicAdd(&h[n*D_MODEL + col], wgt * acc[mi][ni][r]);
                }
            }
        }
}

// ---------------- flash attention (round-4 proven: f32 q/k/v, split-bf16 inside) ----------------
__global__ __launch_bounds__(256) void attn_kernel(
    const float* __restrict__ q, const float* __restrict__ k,
    const float* __restrict__ v, float* __restrict__ att)
{
    __shared__ __align__(16) unsigned short Qs[3][64*72];
    __shared__ __align__(16) unsigned short KP[3][2560];
    __shared__ __align__(16) unsigned short Vt[3][2560];

    int qt = blockIdx.x, bh = blockIdx.y;
    int b = bh >> 4, hh = bh & 15;
    int tid = threadIdx.x, w = tid >> 6, lane = tid & 63;
    int lr = lane & 15, lg = lane >> 4;
    int lrow = tid >> 4;
    int lcol = (tid & 15) << 2;

    const float* qbase = q + ((long)(b*SEQ + qt*64) * D_MODEL + hh*64);
    #pragma unroll
    for (int p = 0; p < 4; p++) {
        int r = p*16 + lrow;
        f32x4 vv = *(const f32x4*)(qbase + (long)r * D_MODEL + lcol);
        #pragma unroll
        for (int jj = 0; jj < 4; jj++) {
            unsigned short h,m,l; split3(vv[jj],h,m,l);
            Qs[0][r*72 + lcol + jj] = h;
            Qs[1][r*72 + lcol + jj] = m;
            Qs[2][r*72 + lcol + jj] = l;
        }
    }

    f32x4 zero = {0.f,0.f,0.f,0.f};
    f32x4 oacc[4] = {zero, zero, zero, zero};
    float mrun[4] = {-INFINITY,-INFINITY,-INFINITY,-INFINITY};
    float lrun[4] = {0.f,0.f,0.f,0.f};

    int ntile = 2*qt + 2;
    for (int jt = 0; jt < ntile; jt++) {
        const float* kbase = k + ((long)(b*SEQ + jt*32) * D_MODEL + hh*64);
        const float* vbase = v + ((long)(b*SEQ + jt*32) * D_MODEL + hh*64);
        #pragma unroll
        for (int p = 0; p < 2; p++) {
            int r = p*16 + lrow;
            f32x4 kv4 = *(const f32x4*)(kbase + (long)r * D_MODEL + lcol);
            f32x4 vv4 = *(const f32x4*)(vbase + (long)r * D_MODEL + lcol);
            #pragma unroll
            for (int jj = 0; jj < 4; jj++) {
                unsigned short h,m,l;
                split3(kv4[jj],h,m,l);
                KP[0][r*72 + lcol + jj] = h;
                KP[1][r*72 + lcol + jj] = m;
                KP[2][r*72 + lcol + jj] = l;
                split3(vv4[jj],h,m,l);
                Vt[0][(lcol+jj)*40 + r] = h;
                Vt[1][(lcol+jj)*40 + r] = m;
                Vt[2][(lcol+jj)*40 + r] = l;
            }
        }
        __syncthreads();

        f32x4 s[2] = {zero, zero};
        #pragma unroll
        for (int ks = 0; ks < 2; ks++) {
            bf16x8 qh = *(const bf16x8*)&Qs[0][(w*16 + lr)*72 + ks*32 + lg*8];
            bf16x8 qm = *(const bf16x8*)&Qs[1][(w*16 + lr)*72 + ks*32 + lg*8];
            bf16x8 ql = *(const bf16x8*)&Qs[2][(w*16 + lr)*72 + ks*32 + lg*8];
            #pragma unroll
            for (int ni = 0; ni < 2; ni++) {
                bf16x8 kh = *(const bf16x8*)&KP[0][(ni*16 + lr)*72 + ks*32 + lg*8];
                bf16x8 km = *(const bf16x8*)&KP[1][(ni*16 + lr)*72 + ks*32 + lg*8];
                bf16x8 kl = *(const bf16x8*)&KP[2][(ni*16 + lr)*72 + ks*32 + lg*8];
                s[ni] = MFMA(qh, kh, s[ni]);
                s[ni] = MFMA(qh, km, s[ni]);
                s[ni] = MFMA(qm, kh, s[ni]);
                s[ni] = MFMA(qh, kl, s[ni]);
                s[ni] = MFMA(qm, km, s[ni]);
                s[ni] = MFMA(ql, kh, s[ni]);
            }
        }
        __syncthreads();

        #pragma unroll
        for (int r = 0; r < 4; r++) {
            int qg = qt*64 + w*16 + lg*4 + r;
            float mx = -INFINITY;
            #pragma unroll
            for (int ni = 0; ni < 2; ni++) {
                int kg = jt*32 + ni*16 + lr;
                float val = s[ni][r] * 0.125f;
                if (kg > qg) val = -INFINITY;
                s[ni][r] = val;
                mx = fmaxf(mx, val);
            }
            #pragma unroll
            for (int dd = 1; dd < 16; dd <<= 1)
                mx = fmaxf(mx, __shfl_xor(mx, dd));
            float mnew  = fmaxf(mrun[r], mx);
            float alpha = expf(mrun[r] - mnew);
            float ps = 0.f;
            #pragma unroll
            for (int ni = 0; ni < 2; ni++) {
                float pv = expf(s[ni][r] - mnew);
                s[ni][r] = pv;
                ps += pv;
            }
            #pragma unroll
            for (int dd = 1; dd < 16; dd <<= 1)
                ps += __shfl_xor(ps, dd);
            lrun[r] = lrun[r] * alpha + ps;
            mrun[r] = mnew;
            #pragma unroll
            for (int d = 0; d < 4; d++) oacc[d][r] *= alpha;
            int prow = w*16 + lg*4 + r;
            #pragma unroll
            for (int ni = 0; ni < 2; ni++) {
                unsigned short h,m,l; split3(s[ni][r],h,m,l);
                KP[0][prow*40 + ni*16 + lr] = h;
                KP[1][prow*40 + ni*16 + lr] = m;
                KP[2][prow*40 + ni*16 + lr] = l;
            }
        }
        {
            bf16x8 ph = *(const bf16x8*)&KP[0][(w*16 + lr)*40 + lg*8];
            bf16x8 pm = *(const bf16x8*)&KP[1][(w*16 + lr)*40 + lg*8];
            bf16x8 pl = *(const bf16x8*)&KP[2][(w*16 + lr)*40 + lg*8];
            #pragma unroll
            for (int ni = 0; ni < 4; ni++) {
                bf16x8 vh = *(const bf16x8*)&Vt[0][(ni*16 + lr)*40 + lg*8];
                bf16x8 vm = *(const bf16x8*)&Vt[1][(ni*16 + lr)*40 + lg*8];
                bf16x8 vl = *(const bf16x8*)&Vt[2][(ni*16 + lr)*40 + lg*8];
                oacc[ni] = MFMA(ph, vh, oacc[ni]);
                oacc[ni] = MFMA(ph, vm, oacc[ni]);
                oacc[ni] = MFMA(pm, vh, oacc[ni]);
                oacc[ni] = MFMA(ph, vl, oacc[ni]);
                oacc[ni] = MFMA(pm, vm, oacc[ni]);
                oacc[ni] = MFMA(pl, vh, oacc[ni]);
            }
        }
        __syncthreads();
    }
    float* obase = att + ((long)(b*SEQ + qt*64) * D_MODEL + hh*64);
    #pragma unroll
    for (int r = 0; r < 4; r++) {
        float inv = 1.f / lrun[r];
        #pragma unroll
        for (int ni = 0; ni < 4; ni++)
            obase[(long)(w*16 + lg*4 + r) * D_MODEL + ni*16 + lr] = oacc[ni][r] * inv;
    }
}

// ---------------- logits: A plane0 x B=emb (BT), f32 out ----------------
__global__ __launch_bounds__(256) void logits_kernel(
    const unsigned short* __restrict__ A0, const float* __restrict__ Bmat, float* __restrict__ C)
{
    __shared__ __align__(16) unsigned short As[128*LDSS];
    __shared__ __align__(16) unsigned short Bs[128*LDSS];
    int n0 = blockIdx.y * 128;   // vocab
    int m0 = blockIdx.x * 128;   // tokens
    int tid = threadIdx.x, w = tid >> 6, lane = tid & 63;
    int wm = (w >> 1)*64, wn = (w & 1)*64;
    int lr = lane & 15, lg = lane >> 4;
    f32x4 zero = {0.f,0.f,0.f,0.f};
    f32x4 acc[4][4];
    #pragma unroll
    for (int mi = 0; mi < 4; mi++)
        #pragma unroll
        for (int ni = 0; ni < 4; ni++) acc[mi][ni] = zero;
    int rb = tid >> 3, kc = (tid & 7) << 2;
    for (int k0 = 0; k0 < D_MODEL; k0 += 32) {
        #pragma unroll
        for (int p = 0; p < 4; p++) {
            int r = p*32 + rb;
            *(u16x4*)&As[r*LDSS + kc] = *(const u16x4*)(A0 + (long)(m0+r)*D_MODEL + k0 + kc);
            f32x4 vv = *(const f32x4*)(Bmat + (long)(n0+r)*D_MODEL + k0 + kc);
            u16x4 hv;
            #pragma unroll
            for (int j = 0; j < 4; j++) hv[j] = f2bf(vv[j]);
            *(u16x4*)&Bs[r*LDSS + kc] = hv;
        }
        __syncthreads();
        bf16x8 bfv[4], af[4];
        #pragma unroll
        for (int ni = 0; ni < 4; ni++)
            bfv[ni] = *(const bf16x8*)&Bs[(wn + ni*16 + lr)*LDSS + lg*8];
        #pragma unroll
        for (int mi = 0; mi < 4; mi++)
            af[mi] = *(const bf16x8*)&As[(wm + mi*16 + lr)*LDSS + lg*8];
        #pragma unroll
        for (int mi = 0; mi < 4; mi++)
            #pragma unroll
            for (int ni = 0; ni < 4; ni++)
                acc[mi][ni] = MFMA(af[mi], bfv[ni], acc[mi][ni]);
        __syncthreads();
    }
    #pragma unroll
    for (int mi = 0; mi < 4; mi++)
        #pragma unroll
        for (int r = 0; r < 4; r++) {
            long row = m0 + wm + mi*16 + lg*4 + r;
            #pragma unroll
            for (int ni = 0; ni < 4; ni++) {
                int col = n0 + wn + ni*16 + lr;
                C[row*VOCAB + col] = acc[mi][ni][r];
            }
        }
}

// ---------------- small kernels ----------------
__global__ __launch_bounds__(256) void embed_kernel(const int* __restrict__ tok,
    const float* __restrict__ emb, float* __restrict__ h)
{
    int n = blockIdx.x;
    int c = threadIdx.x << 2;
    long t = tok[n];
    *(f32x4*)(h + (long)n*D_MODEL + c) = *(const f32x4*)(emb + t*D_MODEL + c);
}

__global__ __launch_bounds__(256) void ropetab_kernel(float* __restrict__ tab)
{
    int idx = blockIdx.x * 256 + threadIdx.x;
    if (idx >= SEQ * 32) return;
    int t = idx >> 5, i = idx & 31;
    double inv = pow(10000.0, -(double)(2*i) / 64.0);
    double ang = (double)t * inv;
    tab[idx*2]   = (float)cos(ang);
    tab[idx*2+1] = (float)sin(ang);
}

__global__ __launch_bounds__(256) void rope_kernel(float* __restrict__ q, float* __restrict__ kk,
    const float* __restrict__ tab)
{
    int gid = blockIdx.x * 256 + threadIdx.x;
    if (gid >= NTOK * 512) return;
    int n   = gid >> 9;
    int rem = gid & 511;
    int hh  = rem >> 5;
    int i   = rem & 31;
    int t   = n & (SEQ - 1);
    float cs = tab[(t*32 + i)*2];
    float sn = tab[(t*32 + i)*2 + 1];
    long base = (long)n * D_MODEL + hh*64 + 2*i;
    float qr = q[base], qi = q[base+1];
    q[base]   = qr*cs - qi*sn;
    q[base+1] = qr*sn + qi*cs;
    float kr = kk[base], ki = kk[base+1];
    kk[base]   = kr*cs - ki*sn;
    kk[base+1] = kr*sn + ki*cs;
}

__global__ __launch_bounds__(64) void gate_kernel(const unsigned short* __restrict__ xf3,
    const float* __restrict__ gw, int* __restrict__ counts,
    int* __restrict__ eid, float* __restrict__ wts, float* __restrict__ pbuf)
{
    int n = blockIdx.x;
    int lane = threadIdx.x;
    float acc[8] = {0,0,0,0,0,0,0,0};
    for (int d0 = lane*4; d0 < D_MODEL; d0 += 256) {
        long idx = (long)n*D_MODEL + d0;
        u16x4 xh = *(const u16x4*)(xf3 + 0*PSA + idx);
        u16x4 xm = *(const u16x4*)(xf3 + 1*PSA + idx);
        u16x4 xl = *(const u16x4*)(xf3 + 2*PSA + idx);
        #pragma unroll
        for (int j = 0; j < 4; j++) {
            float xv = bf2f(xh[j]) + bf2f(xm[j]) + bf2f(xl[j]);
            const float* g = gw + (d0+j) * 8;
            #pragma unroll
            for (int e = 0; e < 8; e++) acc[e] += xv * g[e];
        }
    }
    #pragma unroll
    for (int e = 0; e < 8; e++) {
        #pragma unroll
        for (int dd = 32; dd; dd >>= 1) acc[e] += __shfl_xor(acc[e], dd);
    }
    if (lane == 0) {
        float mx = acc[0];
        #pragma unroll
        for (int e = 1; e < 8; e++) mx = fmaxf(mx, acc[e]);
        float pe[8], ssum = 0.f;
        #pragma unroll
        for (int e = 0; e < 8; e++) { pe[e] = expf(acc[e] - mx); ssum += pe[e]; }
        float sinv = 1.f / ssum;
        #pragma unroll
        for (int e = 0; e < 8; e++) { pe[e] *= sinv; pbuf[n*8 + e] = pe[e]; }
        int e1 = 0;
        #pragma unroll
        for (int e = 1; e < 8; e++) if (pe[e] > pe[e1]) e1 = e;
        int e2 = -1;
        #pragma unroll
        for (int e = 0; e < 8; e++) if (e != e1 && (e2 < 0 || pe[e] > pe[e2])) e2 = e;
        float v1 = pe[e1], v2 = pe[e2];
        float wsum = v1 + v2 + 1e-8f;
        eid[n*2] = e1; eid[n*2+1] = e2;
        wts[n*2] = v1 / wsum; wts[n*2+1] = v2 / wsum;
        atomicAdd(counts + e1, 1);
        atomicAdd(counts + e2, 1);
    }
}

__global__ __launch_bounds__(64) void scan_kernel(const int* __restrict__ counts,
    int* __restrict__ offs, int* __restrict__ cursor,
    const float* __restrict__ pbuf, float* __restrict__ aux)
{
    int t = threadIdx.x;
    int e = t & 7, c = t >> 3;
    float s = 0.f;
    for (int n = 0; n < NTOK/8; n++)
        s += pbuf[(c*(NTOK/8) + n)*8 + e];
    #pragma unroll
    for (int dd = 8; dd < 64; dd <<= 1) s += __shfl_xor(s, dd);
    __shared__ float red[8];
    if (t < 8) red[t] = s;
    __syncthreads();
    if (t == 0) {
        int o = 0; float a = 0.f;
        for (int k = 0; k < 8; k++) {
            offs[k] = o; cursor[k] = o; o += counts[k];
            a += (float)counts[k] * red[k];
        }
        aux[0] += 8.f * a / ((float)NTOK * (float)NTOK);
    }
}

__global__ __launch_bounds__(256) void assign_kernel(const int* __restrict__ eid,
    const float* __restrict__ wts, int* __restrict__ cursor,
    int* __restrict__ rowidx, float* __restrict__ wrow)
{
    int n = blockIdx.x * 256 + threadIdx.x;
    if (n >= NTOK) return;
    #pragma unroll
    for (int s = 0; s < 2; s++) {
        int e = eid[n*2 + s];
        int p = atomicAdd(cursor + e, 1);
        rowidx[p] = n;
        wrow[p] = wts[n*2 + s];
    }
}

__global__ void write_aux_kernel(float* __restrict__ out, const float* __restrict__ aux)
{
    if (threadIdx.x == 0 && blockIdx.x == 0)
        out[(long)NTOK * VOCAB] = aux[0];
}

// ---------------- launch ----------------
extern "C" void kernel_launch(void* const* d_in, const int* in_sizes, int n_in,
                              void* d_out, int out_size, void* d_ws, size_t ws_size,
                              hipStream_t stream)
{
    const int*   tokens = (const int*)d_in[0];
    const float* emb    = (const float*)d_in[1];
    const float* anw    = (const float*)d_in[2];
    const float* wq     = (const float*)d_in[3];
    const float* wk     = (const float*)d_in[4];
    const float* wv     = (const float*)d_in[5];
    const float* wo     = (const float*)d_in[6];
    const float* fnw    = (const float*)d_in[7];
    const float* gw     = (const float*)d_in[8];
    const float* w1     = (const float*)d_in[9];
    const float* w2     = (const float*)d_in[10];
    const float* w3     = (const float*)d_in[11];
    const float* finw   = (const float*)d_in[12];
    float* out = (float*)d_out;

    char* W = (char*)d_ws;
    const size_t MB = 1024u * 1024u;
    // ctrl block [0, 1MB)
    int*   counts = (int*)(W + 0);
    int*   offs   = (int*)(W + 64);
    int*   cursor = (int*)(W + 128);
    float* aux    = (float*)(W + 192);
    int*   eid    = (int*)(W + 4096);
    float* wts    = (float*)(W + 4096 + 16384);
    int*   rowix  = (int*)(W + 4096 + 32768);
    float* wrow   = (float*)(W + 4096 + 49152);
    float* pbuf   = (float*)(W + 4096 + 65536);
    float* rtab   = (float*)(W + 4096 + 131072 + 65536);
    // big buffers — lifetimes:
    //   wq3/wk3/wv3 [45,63) live wsplitT -> qkv
    //   att [45,53) live attn -> wo (weight planes dead)
    //   g [21,53) MoE phase (qkv f32 + att dead)
    // peak 63 MB
    float*          h    = (float*)(W + 1*MB);                   // [1,9)
    unsigned short* hn3  = (unsigned short*)(W + 9*MB);          // [9,21)
    float*          qf   = (float*)(W + 21*MB);                  // [21,29)
    float*          kf   = (float*)(W + 29*MB);                  // [29,37)
    float*          vf   = (float*)(W + 37*MB);                  // [37,45)
    unsigned short* wq3  = (unsigned short*)(W + 45*MB);         // [45,51)
    unsigned short* wk3  = (unsigned short*)(W + 51*MB);         // [51,57)
    unsigned short* wv3  = (unsigned short*)(W + 57*MB);         // [57,63)
    float*          att  = (float*)(W + 45*MB);                  // [45,53)
    float*          g    = (float*)(W + 21*MB);                  // [21,53) MoE phase

    hipMemsetAsync(W, 0, 256, stream);
    ropetab_kernel<<<(SEQ*32 + 255)/256, 256, 0, stream>>>(rtab);
    embed_kernel<<<NTOK, 256, 0, stream>>>(tokens, emb, h);

    for (int l = 0; l < 2; l++) {
        const float* wql = wq + (size_t)l*D_MODEL*D_MODEL;
        const float* wkl = wk + (size_t)l*D_MODEL*D_MODEL;
        const float* wvl = wv + (size_t)l*D_MODEL*D_MODEL;
        const float* wol = wo + (size_t)l*D_MODEL*D_MODEL;

        rmsnorm_kernel<<<NTOK, 256, 0, stream>>>(h, anw + (size_t)l*D_MODEL, hn3);
        wsplitT_kernel<<<dim3(16, 16, 3), 256, 0, stream>>>(wql, wkl, wvl, wq3, wk3, wv3);
        qkv_kernel<<<dim3(D_MODEL/64, NTOK/64, 3), 256, 0, stream>>>(hn3, wq3, wk3, wv3, qf, kf, vf);
        rope_kernel<<<(NTOK*512 + 255)/256, 256, 0, stream>>>(qf, kf, rtab);
        attn_kernel<<<dim3(SEQ/64, BATCH*NHEADS), 256, 0, stream>>>(qf, kf, vf, att);
        wo_kernel<<<dim3(D_MODEL/64, NTOK/64), 256, 0, stream>>>(att, wol, h);

        rmsnorm_kernel<<<NTOK, 256, 0, stream>>>(h, fnw + (size_t)l*D_MODEL, hn3);
        hipMemsetAsync(W, 0, 160, stream);   // counts/offs/cursor (aux preserved @192)
        gate_kernel<<<NTOK, 64, 0, stream>>>(hn3, gw + (size_t)l*D_MODEL*NEXP, counts, eid, wts, pbuf);
        scan_kernel<<<1, 64, 0, stream>>>(counts, offs, cursor, pbuf, aux);
        assign_kernel<<<(NTOK + 255)/256, 256, 0, stream>>>(eid, wts, cursor, rowix, wrow);

        const float* w1l = w1 + (size_t)l*NEXP*D_MODEL*FFH;
        const float* w3l = w3 + (size_t)l*NEXP*D_MODEL*FFH;
        const float* w2l = w2 + (size_t)l*NEXP*FFH*D_MODEL;
        dim3 g13(FFH/128, 2*NTOK/64, NEXP);
        dim3 g2d(D_MODEL/64, 2*NTOK/64, NEXP);
        if (l == 0) {
            moe13_kernel<3><<<g13, 256, 0, stream>>>(hn3, w1l, w3l, g, rowix, counts, offs);
            w2_kernel<3><<<g2d, 256, 0, stream>>>(g, w2l, h, rowix, wrow, counts, offs);
        } else {
            moe13_kernel<1><<<g13, 256, 0, stream>>>(hn3, w1l, w3l, g, rowix, counts, offs);
            w2_kernel<1><<<g2d, 256, 0, stream>>>(g, w2l, h, rowix, wrow, counts, offs);
        }
    }

    rmsnorm_kernel<<<NTOK, 256, 0, stream>>>(h, finw, hn3);
    logits_kernel<<<dim3(NTOK/128, VOCAB/128), 256, 0, stream>>>(hn3, emb, out);
    write_aux_kernel<<<1, 1, 0, stream>>>(out, aux);
}